// Round 6
// baseline (169.141 us; speedup 1.0000x reference)
//
#include <hip/hip_runtime.h>

#define B_ 8
#define A_ 1024
#define N_ 64
#define G_ 50
#define F_ 128
#define ATOMS 4

typedef __attribute__((ext_vector_type(8))) short bf16x8;
typedef __attribute__((ext_vector_type(4))) float f32x4;

__device__ __forceinline__ float sspf(float v) {
    return fmaxf(v, 0.f) + __logf(1.f + __expf(-fabsf(v))) - 0.69314718055994530942f;
}
__device__ __forceinline__ unsigned short f2bf(float f) {
    unsigned u = __float_as_uint(f);
    u += 0x7fffu + ((u >> 16) & 1u);
    return (unsigned short)(u >> 16);
}
__device__ __forceinline__ unsigned cvt_pk(float lo, float hi) {
    unsigned r;
    asm("v_cvt_pk_bf16_f32 %0, %1, %2" : "=v"(r) : "v"(lo), "v"(hi));
    return r;
}
// butterfly sum over l16 (xor 1,2,4,8) via ds_swizzle immediates
__device__ __forceinline__ float red16(float p) {
    p += __int_as_float(__builtin_amdgcn_ds_swizzle(__float_as_int(p), 0x041F));
    p += __int_as_float(__builtin_amdgcn_ds_swizzle(__float_as_int(p), 0x081F));
    p += __int_as_float(__builtin_amdgcn_ds_swizzle(__float_as_int(p), 0x101F));
    p += __int_as_float(__builtin_amdgcn_ds_swizzle(__float_as_int(p), 0x201F));
    return p;
}

// Pack all four [K x 128] weights into MFMA fragment order:
// P[((ks*8+nt)*64+lane)*8+i] = W[(32ks+8*(lane>>4)+i)*128 + 16nt+(lane&15)]
// For W1 (K=50), row k==50 holds b_f1 (bias folded via f_ij pad element = 1).
__global__ __launch_bounds__(256) void pack_all(
    const float* __restrict__ W1, const float* __restrict__ b1,
    const float* __restrict__ W2, const float* __restrict__ Wi,
    const float* __restrict__ Wo,
    unsigned short* __restrict__ P1, unsigned short* __restrict__ P2,
    unsigned short* __restrict__ Pi, unsigned short* __restrict__ Po)
{
    int blk = blockIdx.x;
    const float* W; const float* bias = nullptr; unsigned short* P; int K, id;
    if (blk < 32)       { W = W1; P = P1; K = 50;  id = blk * 256 + threadIdx.x; bias = b1; }
    else if (blk < 96)  { W = W2; P = P2; K = 128; id = (blk - 32) * 256 + threadIdx.x; }
    else if (blk < 160) { W = Wi; P = Pi; K = 128; id = (blk - 96) * 256 + threadIdx.x; }
    else                { W = Wo; P = Po; K = 128; id = (blk - 160) * 256 + threadIdx.x; }
    int i    = id & 7;
    int lane = (id >> 3) & 63;
    int nt   = (id >> 9) & 7;
    int ks   = id >> 12;
    int k = 32 * ks + 8 * (lane >> 4) + i;
    int f = 16 * nt + (lane & 15);
    float v = (k < K) ? W[k * F_ + f] : ((bias && k == K) ? bias[f] : 0.f);
    P[id] = f2bf(v);
}

// out[R x 128] = (ACT? ssp : id)(A[R x 128] @ Bpacked + bias). 1 wave per 16 rows.
template <bool ACT, bool OUT_BF16>
__global__ __launch_bounds__(64) void rowgemm_kernel(
    const float* Afp, const unsigned short* __restrict__ Bp,
    const float* __restrict__ bias, void* outv)
{
    const int l  = threadIdx.x;
    const int r0 = blockIdx.x * 16;
    const bf16x8* Bv = (const bf16x8*)Bp;

    f32x4 acc[8];
    #pragma unroll
    for (int nt = 0; nt < 8; ++nt) acc[nt] = f32x4{0.f, 0.f, 0.f, 0.f};

    const int arow = r0 + (l & 15);
    const int koff = (l >> 4) * 8;
    #pragma unroll
    for (int ks = 0; ks < 4; ++ks) {
        const float* ap = Afp + (size_t)arow * F_ + ks * 32 + koff;
        float4 a0 = *(const float4*)ap;
        float4 a1 = *(const float4*)(ap + 4);
        bf16x8 af;
        af[0] = (short)f2bf(a0.x); af[1] = (short)f2bf(a0.y);
        af[2] = (short)f2bf(a0.z); af[3] = (short)f2bf(a0.w);
        af[4] = (short)f2bf(a1.x); af[5] = (short)f2bf(a1.y);
        af[6] = (short)f2bf(a1.z); af[7] = (short)f2bf(a1.w);
        #pragma unroll
        for (int nt = 0; nt < 8; ++nt) {
            bf16x8 bf = Bv[(ks * 8 + nt) * 64 + l];
            acc[nt] = __builtin_amdgcn_mfma_f32_16x16x32_bf16(af, bf, acc[nt], 0, 0, 0);
        }
    }
    #pragma unroll
    for (int nt = 0; nt < 8; ++nt) {
        int f = nt * 16 + (l & 15);
        float bv = bias ? bias[f] : 0.f;
        #pragma unroll
        for (int r = 0; r < 4; ++r) {
            int orow = r0 + (l >> 4) * 4 + r;
            float v = acc[nt][r] + bv;
            if (ACT) v = sspf(v);
            if (OUT_BF16) ((unsigned short*)outv)[(size_t)orow * F_ + f] = f2bf(v);
            else          ((float*)outv)[(size_t)orow * F_ + f] = v;
        }
    }
}

// 4 atoms/block, software-pipelined, single fij buffer (24 KB LDS), 5 blocks/CU.
__global__ __launch_bounds__(256, 5) void cfconv_main(
    const unsigned short* __restrict__ xt,   // [B*A][F] bf16
    const float* __restrict__ mask,          // [B,A,N]
    const int*   __restrict__ nbr,           // [B,A,N]
    const float* __restrict__ fij,           // [B,A,N,G]
    const unsigned short* __restrict__ W1s,  // packed, K=50 (+bias row 50)
    const unsigned short* __restrict__ W2s,  // packed, K=128
    const float* __restrict__ bf2,
    float* __restrict__ Y)                   // [B*A][F] pre-output
{
    const int bid = blockIdx.x;
    const int swz = (bid & 7) * (2048 / 8) + (bid >> 3);   // XCD-bijective (2048%8==0)
    const int ba0 = swz * ATOMS;
    const int t   = threadIdx.x;
    const int w   = t >> 6;
    const int l   = t & 63;
    const int l16 = l & 15;
    const int q   = l >> 4;

    __shared__ unsigned short s_fp[4096];   // fij frags, 8 KB (single buffer)
    __shared__ unsigned short s_hp[8192];   // H frags, 16 KB

    // ---- uniform bases (SADDR-form addressing) ----
    const unsigned short* xt_b = xt + ((size_t)(ba0 >> 10) << 10) * F_;  // this block's b
    const int xoff = 32 * w + 4 * q;        // f2=0 feature offset; f2=1 adds 16

    // ---- W fragments resident for the whole block ----
    const bf16x8* w1v = (const bf16x8*)W1s;
    const bf16x8* w2v = (const bf16x8*)W2s;
    bf16x8 W1r[2][2], W2r[4][2];
    #pragma unroll
    for (int ks = 0; ks < 2; ++ks) {
        W1r[ks][0] = w1v[(ks * 8 + 2 * w + 0) * 64 + l];
        W1r[ks][1] = w1v[(ks * 8 + 2 * w + 1) * 64 + l];
    }
    #pragma unroll
    for (int ks = 0; ks < 4; ++ks) {
        W2r[ks][0] = w2v[(ks * 8 + 2 * w + 0) * 64 + l];
        W2r[ks][1] = w2v[(ks * 8 + 2 * w + 1) * 64 + l];
    }
    f32x4 b2acc[2];
    {
        float4 t0 = *(const float4*)(bf2 + 16 * (2 * w + 0) + 4 * q);
        float4 t1 = *(const float4*)(bf2 + 16 * (2 * w + 1) + 4 * q);
        b2acc[0] = f32x4{t0.x, t0.y, t0.z, t0.w};
        b2acc[1] = f32x4{t1.x, t1.y, t1.z, t1.w};
    }

    // ---- prologue: atom 0 inputs ----
    int nbv[4]; float mkv[4];
    {
        const int*   nb0 = nbr  + (size_t)ba0 * N_;
        const float* mk0 = mask + (size_t)ba0 * N_;
        #pragma unroll
        for (int nt = 0; nt < 4; ++nt) {
            nbv[nt] = nb0[16 * nt + l16];
            mkv[nt] = mk0[16 * nt + l16];
        }
    }
    float2 fa[4], fb[4];
    {
        const float* frow = fij + (size_t)ba0 * (N_ * G_) + (16 * w + l16) * G_;
        #pragma unroll
        for (int j = 0; j < 4; ++j) fa[j] = *(const float2*)(frow + 8 * q + 2 * j);
        if (q < 2) {
            #pragma unroll
            for (int j = 0; j < 4; ++j) fb[j] = *(const float2*)(frow + 32 + 8 * q + 2 * j);
        } else if (q == 2) {
            fb[0] = *(const float2*)(frow + 48);
            fb[1] = float2{1.f, 0.f};  // g=50: bias row of W1
            fb[2] = float2{0.f, 0.f}; fb[3] = float2{0.f, 0.f};
        } else {
            #pragma unroll
            for (int j = 0; j < 4; ++j) fb[j] = float2{0.f, 0.f};
        }
    }
    uint2 xg[2][4];
    #pragma unroll
    for (int f2 = 0; f2 < 2; ++f2)
        #pragma unroll
        for (int nt = 0; nt < 4; ++nt)
            xg[f2][nt] = *(const uint2*)(xt_b + nbv[nt] * F_ + xoff + 16 * f2);
    {
        uint4 pk0, pk1;
        pk0.x = cvt_pk(fa[0].x, fa[0].y); pk0.y = cvt_pk(fa[1].x, fa[1].y);
        pk0.z = cvt_pk(fa[2].x, fa[2].y); pk0.w = cvt_pk(fa[3].x, fa[3].y);
        pk1.x = cvt_pk(fb[0].x, fb[0].y); pk1.y = cvt_pk(fb[1].x, fb[1].y);
        pk1.z = cvt_pk(fb[2].x, fb[2].y); pk1.w = cvt_pk(fb[3].x, fb[3].y);
        *(uint4*)(&s_fp[((w * 2 + 0) * 64 + l) * 8]) = pk0;
        *(uint4*)(&s_fp[((w * 2 + 1) * 64 + l) * 8]) = pk1;
    }
    __syncthreads();

    int nbv2[4]; float mkv2[4];

    #pragma unroll
    for (int i = 0; i < ATOMS; ++i) {
        const int ba = ba0 + i;

        // ---- GEMM1 (ks=0 peeled with zero C): acc1[ct2][nt] ----
        const bf16x8* fv = (const bf16x8*)s_fp;
        f32x4 acc1[2][4];
        __builtin_amdgcn_s_setprio(1);
        {
            bf16x8 bb[4];
            #pragma unroll
            for (int nt = 0; nt < 4; ++nt) bb[nt] = fv[(nt * 2 + 0) * 64 + l];
            #pragma unroll
            for (int nt = 0; nt < 4; ++nt) {
                acc1[0][nt] = __builtin_amdgcn_mfma_f32_16x16x32_bf16(W1r[0][0], bb[nt], f32x4{0.f,0.f,0.f,0.f}, 0, 0, 0);
                acc1[1][nt] = __builtin_amdgcn_mfma_f32_16x16x32_bf16(W1r[0][1], bb[nt], f32x4{0.f,0.f,0.f,0.f}, 0, 0, 0);
            }
            #pragma unroll
            for (int nt = 0; nt < 4; ++nt) bb[nt] = fv[(nt * 2 + 1) * 64 + l];
            #pragma unroll
            for (int nt = 0; nt < 4; ++nt) {
                acc1[0][nt] = __builtin_amdgcn_mfma_f32_16x16x32_bf16(W1r[1][0], bb[nt], acc1[0][nt], 0, 0, 0);
                acc1[1][nt] = __builtin_amdgcn_mfma_f32_16x16x32_bf16(W1r[1][1], bb[nt], acc1[1][nt], 0, 0, 0);
            }
        }
        __builtin_amdgcn_s_setprio(0);

        // ---- issue next atom's fij + nbr/mask (fly under epilogue) ----
        if (i < ATOMS - 1) {
            const float* frow = fij + (size_t)(ba + 1) * (N_ * G_) + (16 * w + l16) * G_;
            #pragma unroll
            for (int j = 0; j < 4; ++j) fa[j] = *(const float2*)(frow + 8 * q + 2 * j);
            if (q < 2) {
                #pragma unroll
                for (int j = 0; j < 4; ++j) fb[j] = *(const float2*)(frow + 32 + 8 * q + 2 * j);
            } else if (q == 2) {
                fb[0] = *(const float2*)(frow + 48);
                fb[1] = float2{1.f, 0.f};
                fb[2] = float2{0.f, 0.f}; fb[3] = float2{0.f, 0.f};
            } else {
                #pragma unroll
                for (int j = 0; j < 4; ++j) fb[j] = float2{0.f, 0.f};
            }
            const int*   nb1 = nbr  + (size_t)(ba + 1) * N_;
            const float* mk1 = mask + (size_t)(ba + 1) * N_;
            #pragma unroll
            for (int nt = 0; nt < 4; ++nt) {
                nbv2[nt] = nb1[16 * nt + l16];
                mkv2[nt] = mk1[16 * nt + l16];
            }
        }

        // ---- H epilogue: ssp -> B-frag layout (bias pre-folded via pad row) ----
        #pragma unroll
        for (int ct2 = 0; ct2 < 2; ++ct2) {
            const int addr = ((w * 64 + 16 * (2 * ct2 + (q >> 1)) + l16) * 8 + 4 * (q & 1));
            #pragma unroll
            for (int nt = 0; nt < 4; ++nt) {
                float h0 = sspf(acc1[ct2][nt][0]);
                float h1 = sspf(acc1[ct2][nt][1]);
                float h2 = sspf(acc1[ct2][nt][2]);
                float h3 = sspf(acc1[ct2][nt][3]);
                uint2 pk;
                pk.x = cvt_pk(h0, h1);
                pk.y = cvt_pk(h2, h3);
                *(uint2*)(&s_hp[nt * 2048 + addr]) = pk;
            }
        }
        __syncthreads();   // B1: fij reads done AND H frags ready

        // ---- stage next fij frags into s_fp (concurrent with GEMM2) ----
        if (i < ATOMS - 1) {
            uint4 pk0, pk1;
            pk0.x = cvt_pk(fa[0].x, fa[0].y); pk0.y = cvt_pk(fa[1].x, fa[1].y);
            pk0.z = cvt_pk(fa[2].x, fa[2].y); pk0.w = cvt_pk(fa[3].x, fa[3].y);
            pk1.x = cvt_pk(fb[0].x, fb[0].y); pk1.y = cvt_pk(fb[1].x, fb[1].y);
            pk1.z = cvt_pk(fb[2].x, fb[2].y); pk1.w = cvt_pk(fb[3].x, fb[3].y);
            *(uint4*)(&s_fp[((w * 2 + 0) * 64 + l) * 8]) = pk0;
            *(uint4*)(&s_fp[((w * 2 + 1) * 64 + l) * 8]) = pk1;
        }

        // ---- GEMM2 (ks=0 peeled with C = bias2): acc2[f2][nt] ----
        const bf16x8* hv = (const bf16x8*)s_hp;
        f32x4 acc2[2][4];
        __builtin_amdgcn_s_setprio(1);
        {
            bf16x8 bb[4];
            #pragma unroll
            for (int nt = 0; nt < 4; ++nt) bb[nt] = hv[(nt * 4 + 0) * 64 + l];
            #pragma unroll
            for (int nt = 0; nt < 4; ++nt) {
                acc2[0][nt] = __builtin_amdgcn_mfma_f32_16x16x32_bf16(W2r[0][0], bb[nt], b2acc[0], 0, 0, 0);
                acc2[1][nt] = __builtin_amdgcn_mfma_f32_16x16x32_bf16(W2r[0][1], bb[nt], b2acc[1], 0, 0, 0);
            }
            #pragma unroll
            for (int ks = 1; ks < 4; ++ks) {
                #pragma unroll
                for (int nt = 0; nt < 4; ++nt) bb[nt] = hv[(nt * 4 + ks) * 64 + l];
                #pragma unroll
                for (int nt = 0; nt < 4; ++nt) {
                    acc2[0][nt] = __builtin_amdgcn_mfma_f32_16x16x32_bf16(W2r[ks][0], bb[nt], acc2[0][nt], 0, 0, 0);
                    acc2[1][nt] = __builtin_amdgcn_mfma_f32_16x16x32_bf16(W2r[ks][1], bb[nt], acc2[1][nt], 0, 0, 0);
                }
            }
        }
        __builtin_amdgcn_s_setprio(0);

        // ---- reduce over m: filter * mask * x, swizzle-butterfly, store ----
        #pragma unroll
        for (int f2 = 0; f2 < 2; ++f2) {
            float p0 = 0.f, p1 = 0.f, p2 = 0.f, p3 = 0.f;
            #pragma unroll
            for (int nt = 0; nt < 4; ++nt) {
                const float msk = mkv[nt];
                const uint2 xv = xg[f2][nt];
                const float x0 = __uint_as_float(xv.x << 16);
                const float x1 = __uint_as_float(xv.x & 0xffff0000u);
                const float x2 = __uint_as_float(xv.y << 16);
                const float x3 = __uint_as_float(xv.y & 0xffff0000u);
                p0 = fmaf(msk * acc2[f2][nt][0], x0, p0);
                p1 = fmaf(msk * acc2[f2][nt][1], x1, p1);
                p2 = fmaf(msk * acc2[f2][nt][2], x2, p2);
                p3 = fmaf(msk * acc2[f2][nt][3], x3, p3);
            }
            p0 = red16(p0); p1 = red16(p1); p2 = red16(p2); p3 = red16(p3);
            if (l16 == 0)
                *(float4*)(Y + (size_t)ba * F_ + 16 * (2 * w + f2) + 4 * q) = float4{p0, p1, p2, p3};
        }

        // ---- roll inputs; issue next xg gathers ----
        if (i < ATOMS - 1) {
            #pragma unroll
            for (int nt = 0; nt < 4; ++nt) { nbv[nt] = nbv2[nt]; mkv[nt] = mkv2[nt]; }
            #pragma unroll
            for (int f2 = 0; f2 < 2; ++f2)
                #pragma unroll
                for (int nt = 0; nt < 4; ++nt)
                    xg[f2][nt] = *(const uint2*)(xt_b + nbv[nt] * F_ + xoff + 16 * f2);
        }
        __syncthreads();   // B2: s_fp staged for i+1; H reads done
    }
}

extern "C" void kernel_launch(void* const* d_in, const int* in_sizes, int n_in,
                              void* d_out, int out_size, void* d_ws, size_t ws_size,
                              hipStream_t stream) {
    const float* x     = (const float*)d_in[0];
    const float* mask  = (const float*)d_in[1];
    const int*   nbr   = (const int*)d_in[2];
    const float* fij   = (const float*)d_in[3];
    const float* Wf1   = (const float*)d_in[4];
    const float* bf1   = (const float*)d_in[5];
    const float* Wf2   = (const float*)d_in[6];
    const float* bf2   = (const float*)d_in[7];
    const float* Win2f = (const float*)d_in[8];
    const float* Wout  = (const float*)d_in[9];
    const float* bout  = (const float*)d_in[10];
    float* out = (float*)d_out;

    char* ws = (char*)d_ws;
    unsigned short* W1p   = (unsigned short*)(ws);            // 16 KB
    unsigned short* W2p   = (unsigned short*)(ws + 16384);    // 32 KB
    unsigned short* Winp  = (unsigned short*)(ws + 49152);    // 32 KB
    unsigned short* Woutp = (unsigned short*)(ws + 81920);    // 32 KB
    unsigned short* xt    = (unsigned short*)(ws + 114688);   // 2 MB

    pack_all<<<224, 256, 0, stream>>>(Wf1, bf1, Wf2, Win2f, Wout, W1p, W2p, Winp, Woutp);

    rowgemm_kernel<false, true><<<B_ * A_ / 16, 64, 0, stream>>>(x, Winp, nullptr, xt);

    cfconv_main<<<B_ * A_ / ATOMS, 256, 0, stream>>>(xt, mask, nbr, fij, W1p, W2p, bf2, out);

    rowgemm_kernel<true, false><<<B_ * A_ / 16, 64, 0, stream>>>(out, Woutp, bout, out);
}

// Round 7
// 147.838 us; speedup vs baseline: 1.1441x; 1.1441x over previous
//
#include <hip/hip_runtime.h>

#define B_ 8
#define A_ 1024
#define N_ 64
#define G_ 50
#define F_ 128
#define ATOMS 4

typedef __attribute__((ext_vector_type(8))) short bf16x8;
typedef __attribute__((ext_vector_type(4))) float f32x4;

__device__ __forceinline__ float sspf(float v) {
    return fmaxf(v, 0.f) + __logf(1.f + __expf(-fabsf(v))) - 0.69314718055994530942f;
}
__device__ __forceinline__ unsigned short f2bf(float f) {
    unsigned u = __float_as_uint(f);
    u += 0x7fffu + ((u >> 16) & 1u);
    return (unsigned short)(u >> 16);
}
__device__ __forceinline__ unsigned cvt_pk(float lo, float hi) {
    unsigned r;
    asm("v_cvt_pk_bf16_f32 %0, %1, %2" : "=v"(r) : "v"(lo), "v"(hi));
    return r;
}
// butterfly sum over l16 (xor 1,2,4,8) via ds_swizzle immediates
__device__ __forceinline__ float red16(float p) {
    p += __int_as_float(__builtin_amdgcn_ds_swizzle(__float_as_int(p), 0x041F));
    p += __int_as_float(__builtin_amdgcn_ds_swizzle(__float_as_int(p), 0x081F));
    p += __int_as_float(__builtin_amdgcn_ds_swizzle(__float_as_int(p), 0x101F));
    p += __int_as_float(__builtin_amdgcn_ds_swizzle(__float_as_int(p), 0x201F));
    return p;
}

// Pack all four [K x 128] weights into MFMA fragment order:
// P[((ks*8+nt)*64+lane)*8+i] = W[(32ks+8*(lane>>4)+i)*128 + 16nt+(lane&15)]
// For W1 (K=50), row k==50 holds b_f1 (bias folded via f_ij pad element = 1).
__global__ __launch_bounds__(256) void pack_all(
    const float* __restrict__ W1, const float* __restrict__ b1,
    const float* __restrict__ W2, const float* __restrict__ Wi,
    const float* __restrict__ Wo,
    unsigned short* __restrict__ P1, unsigned short* __restrict__ P2,
    unsigned short* __restrict__ Pi, unsigned short* __restrict__ Po)
{
    int blk = blockIdx.x;
    const float* W; const float* bias = nullptr; unsigned short* P; int K, id;
    if (blk < 32)       { W = W1; P = P1; K = 50;  id = blk * 256 + threadIdx.x; bias = b1; }
    else if (blk < 96)  { W = W2; P = P2; K = 128; id = (blk - 32) * 256 + threadIdx.x; }
    else if (blk < 160) { W = Wi; P = Pi; K = 128; id = (blk - 96) * 256 + threadIdx.x; }
    else                { W = Wo; P = Po; K = 128; id = (blk - 160) * 256 + threadIdx.x; }
    int i    = id & 7;
    int lane = (id >> 3) & 63;
    int nt   = (id >> 9) & 7;
    int ks   = id >> 12;
    int k = 32 * ks + 8 * (lane >> 4) + i;
    int f = 16 * nt + (lane & 15);
    float v = (k < K) ? W[k * F_ + f] : ((bias && k == K) ? bias[f] : 0.f);
    P[id] = f2bf(v);
}

// out[R x 128] = (ACT? ssp : id)(A[R x 128] @ Bpacked + bias). 1 wave per 16 rows.
template <bool ACT, bool OUT_BF16>
__global__ __launch_bounds__(64) void rowgemm_kernel(
    const float* Afp, const unsigned short* __restrict__ Bp,
    const float* __restrict__ bias, void* outv)
{
    const int l  = threadIdx.x;
    const int r0 = blockIdx.x * 16;
    const bf16x8* Bv = (const bf16x8*)Bp;

    f32x4 acc[8];
    #pragma unroll
    for (int nt = 0; nt < 8; ++nt) acc[nt] = f32x4{0.f, 0.f, 0.f, 0.f};

    const int arow = r0 + (l & 15);
    const int koff = (l >> 4) * 8;
    #pragma unroll
    for (int ks = 0; ks < 4; ++ks) {
        const float* ap = Afp + (size_t)arow * F_ + ks * 32 + koff;
        float4 a0 = *(const float4*)ap;
        float4 a1 = *(const float4*)(ap + 4);
        bf16x8 af;
        af[0] = (short)f2bf(a0.x); af[1] = (short)f2bf(a0.y);
        af[2] = (short)f2bf(a0.z); af[3] = (short)f2bf(a0.w);
        af[4] = (short)f2bf(a1.x); af[5] = (short)f2bf(a1.y);
        af[6] = (short)f2bf(a1.z); af[7] = (short)f2bf(a1.w);
        #pragma unroll
        for (int nt = 0; nt < 8; ++nt) {
            bf16x8 bf = Bv[(ks * 8 + nt) * 64 + l];
            acc[nt] = __builtin_amdgcn_mfma_f32_16x16x32_bf16(af, bf, acc[nt], 0, 0, 0);
        }
    }
    #pragma unroll
    for (int nt = 0; nt < 8; ++nt) {
        int f = nt * 16 + (l & 15);
        float bv = bias ? bias[f] : 0.f;
        #pragma unroll
        for (int r = 0; r < 4; ++r) {
            int orow = r0 + (l >> 4) * 4 + r;
            float v = acc[nt][r] + bv;
            if (ACT) v = sspf(v);
            if (OUT_BF16) ((unsigned short*)outv)[(size_t)orow * F_ + f] = f2bf(v);
            else          ((float*)outv)[(size_t)orow * F_ + f] = v;
        }
    }
}

// 4 atoms/block, software-pipelined, single fij buffer (24 KB LDS).
__global__ __launch_bounds__(256, 4) void cfconv_main(
    const unsigned short* __restrict__ xt,   // [B*A][F] bf16
    const float* __restrict__ mask,          // [B,A,N]
    const int*   __restrict__ nbr,           // [B,A,N]
    const float* __restrict__ fij,           // [B,A,N,G]
    const unsigned short* __restrict__ W1s,  // packed, K=50 (+bias row 50)
    const unsigned short* __restrict__ W2s,  // packed, K=128
    const float* __restrict__ bf2,
    float* __restrict__ Y)                   // [B*A][F] pre-output
{
    const int bid = blockIdx.x;
    const int swz = (bid & 7) * (2048 / 8) + (bid >> 3);   // XCD-bijective (2048%8==0)
    const int ba0 = swz * ATOMS;
    const int t   = threadIdx.x;
    const int w   = t >> 6;
    const int l   = t & 63;
    const int l16 = l & 15;
    const int q   = l >> 4;

    __shared__ unsigned short s_fp[4096];   // fij frags, 8 KB (single buffer)
    __shared__ unsigned short s_hp[8192];   // H frags, 16 KB

    // ---- uniform bases (SADDR-form addressing) ----
    const unsigned short* xt_b = xt + ((size_t)(ba0 >> 10) << 10) * F_;  // this block's b
    const int xoff = 32 * w + 4 * q;        // f2=0 feature offset; f2=1 adds 16

    // ---- W fragments resident for the whole block ----
    const bf16x8* w1v = (const bf16x8*)W1s;
    const bf16x8* w2v = (const bf16x8*)W2s;
    bf16x8 W1r[2][2], W2r[4][2];
    #pragma unroll
    for (int ks = 0; ks < 2; ++ks) {
        W1r[ks][0] = w1v[(ks * 8 + 2 * w + 0) * 64 + l];
        W1r[ks][1] = w1v[(ks * 8 + 2 * w + 1) * 64 + l];
    }
    #pragma unroll
    for (int ks = 0; ks < 4; ++ks) {
        W2r[ks][0] = w2v[(ks * 8 + 2 * w + 0) * 64 + l];
        W2r[ks][1] = w2v[(ks * 8 + 2 * w + 1) * 64 + l];
    }
    f32x4 b2acc[2];
    {
        float4 t0 = *(const float4*)(bf2 + 16 * (2 * w + 0) + 4 * q);
        float4 t1 = *(const float4*)(bf2 + 16 * (2 * w + 1) + 4 * q);
        b2acc[0] = f32x4{t0.x, t0.y, t0.z, t0.w};
        b2acc[1] = f32x4{t1.x, t1.y, t1.z, t1.w};
    }

    // ---- prologue: atom 0 inputs ----
    int nbv[4]; float mkv[4];
    {
        const int*   nb0 = nbr  + (size_t)ba0 * N_;
        const float* mk0 = mask + (size_t)ba0 * N_;
        #pragma unroll
        for (int nt = 0; nt < 4; ++nt) {
            nbv[nt] = nb0[16 * nt + l16];
            mkv[nt] = mk0[16 * nt + l16];
        }
    }
    float2 fa[4], fb[4];
    {
        const float* frow = fij + (size_t)ba0 * (N_ * G_) + (16 * w + l16) * G_;
        #pragma unroll
        for (int j = 0; j < 4; ++j) fa[j] = *(const float2*)(frow + 8 * q + 2 * j);
        if (q < 2) {
            #pragma unroll
            for (int j = 0; j < 4; ++j) fb[j] = *(const float2*)(frow + 32 + 8 * q + 2 * j);
        } else if (q == 2) {
            fb[0] = *(const float2*)(frow + 48);
            fb[1] = float2{1.f, 0.f};  // g=50: bias row of W1
            fb[2] = float2{0.f, 0.f}; fb[3] = float2{0.f, 0.f};
        } else {
            #pragma unroll
            for (int j = 0; j < 4; ++j) fb[j] = float2{0.f, 0.f};
        }
    }
    uint2 xg[2][4];
    #pragma unroll
    for (int f2 = 0; f2 < 2; ++f2)
        #pragma unroll
        for (int nt = 0; nt < 4; ++nt)
            xg[f2][nt] = *(const uint2*)(xt_b + nbv[nt] * F_ + xoff + 16 * f2);
    {
        uint4 pk0, pk1;
        pk0.x = cvt_pk(fa[0].x, fa[0].y); pk0.y = cvt_pk(fa[1].x, fa[1].y);
        pk0.z = cvt_pk(fa[2].x, fa[2].y); pk0.w = cvt_pk(fa[3].x, fa[3].y);
        pk1.x = cvt_pk(fb[0].x, fb[0].y); pk1.y = cvt_pk(fb[1].x, fb[1].y);
        pk1.z = cvt_pk(fb[2].x, fb[2].y); pk1.w = cvt_pk(fb[3].x, fb[3].y);
        *(uint4*)(&s_fp[((w * 2 + 0) * 64 + l) * 8]) = pk0;
        *(uint4*)(&s_fp[((w * 2 + 1) * 64 + l) * 8]) = pk1;
    }
    __syncthreads();

    int nbv2[4]; float mkv2[4];

    #pragma unroll
    for (int i = 0; i < ATOMS; ++i) {
        const int ba = ba0 + i;

        // ---- issue next atom's fij + nbr/mask FIRST (max latency cover) ----
        if (i < ATOMS - 1) {
            const float* frow = fij + (size_t)(ba + 1) * (N_ * G_) + (16 * w + l16) * G_;
            #pragma unroll
            for (int j = 0; j < 4; ++j) fa[j] = *(const float2*)(frow + 8 * q + 2 * j);
            if (q < 2) {
                #pragma unroll
                for (int j = 0; j < 4; ++j) fb[j] = *(const float2*)(frow + 32 + 8 * q + 2 * j);
            } else if (q == 2) {
                fb[0] = *(const float2*)(frow + 48);
                fb[1] = float2{1.f, 0.f};
                fb[2] = float2{0.f, 0.f}; fb[3] = float2{0.f, 0.f};
            } else {
                #pragma unroll
                for (int j = 0; j < 4; ++j) fb[j] = float2{0.f, 0.f};
            }
            const int*   nb1 = nbr  + (size_t)(ba + 1) * N_;
            const float* mk1 = mask + (size_t)(ba + 1) * N_;
            #pragma unroll
            for (int nt = 0; nt < 4; ++nt) {
                nbv2[nt] = nb1[16 * nt + l16];
                mkv2[nt] = mk1[16 * nt + l16];
            }
        }

        // ---- GEMM1 (ks=0 peeled with zero C): acc1[ct2][nt] ----
        const bf16x8* fv = (const bf16x8*)s_fp;
        f32x4 acc1[2][4];
        __builtin_amdgcn_s_setprio(1);
        {
            bf16x8 bb[4];
            #pragma unroll
            for (int nt = 0; nt < 4; ++nt) bb[nt] = fv[(nt * 2 + 0) * 64 + l];
            #pragma unroll
            for (int nt = 0; nt < 4; ++nt) {
                acc1[0][nt] = __builtin_amdgcn_mfma_f32_16x16x32_bf16(W1r[0][0], bb[nt], f32x4{0.f,0.f,0.f,0.f}, 0, 0, 0);
                acc1[1][nt] = __builtin_amdgcn_mfma_f32_16x16x32_bf16(W1r[0][1], bb[nt], f32x4{0.f,0.f,0.f,0.f}, 0, 0, 0);
            }
            #pragma unroll
            for (int nt = 0; nt < 4; ++nt) bb[nt] = fv[(nt * 2 + 1) * 64 + l];
            #pragma unroll
            for (int nt = 0; nt < 4; ++nt) {
                acc1[0][nt] = __builtin_amdgcn_mfma_f32_16x16x32_bf16(W1r[1][0], bb[nt], acc1[0][nt], 0, 0, 0);
                acc1[1][nt] = __builtin_amdgcn_mfma_f32_16x16x32_bf16(W1r[1][1], bb[nt], acc1[1][nt], 0, 0, 0);
            }
        }
        __builtin_amdgcn_s_setprio(0);

        // ---- H epilogue: ssp -> B-frag layout (bias pre-folded via pad row) ----
        #pragma unroll
        for (int ct2 = 0; ct2 < 2; ++ct2) {
            const int addr = ((w * 64 + 16 * (2 * ct2 + (q >> 1)) + l16) * 8 + 4 * (q & 1));
            #pragma unroll
            for (int nt = 0; nt < 4; ++nt) {
                float h0 = sspf(acc1[ct2][nt][0]);
                float h1 = sspf(acc1[ct2][nt][1]);
                float h2 = sspf(acc1[ct2][nt][2]);
                float h3 = sspf(acc1[ct2][nt][3]);
                uint2 pk;
                pk.x = cvt_pk(h0, h1);
                pk.y = cvt_pk(h2, h3);
                *(uint2*)(&s_hp[nt * 2048 + addr]) = pk;
            }
        }
        __syncthreads();   // B1: fij reads done AND H frags ready

        // ---- GEMM2 (ks=0 peeled with C = bias2): acc2[f2][nt] ----
        const bf16x8* hv = (const bf16x8*)s_hp;
        f32x4 acc2[2][4];
        __builtin_amdgcn_s_setprio(1);
        {
            bf16x8 bb[4];
            #pragma unroll
            for (int nt = 0; nt < 4; ++nt) bb[nt] = hv[(nt * 4 + 0) * 64 + l];
            #pragma unroll
            for (int nt = 0; nt < 4; ++nt) {
                acc2[0][nt] = __builtin_amdgcn_mfma_f32_16x16x32_bf16(W2r[0][0], bb[nt], b2acc[0], 0, 0, 0);
                acc2[1][nt] = __builtin_amdgcn_mfma_f32_16x16x32_bf16(W2r[0][1], bb[nt], b2acc[1], 0, 0, 0);
            }
            #pragma unroll
            for (int ks = 1; ks < 4; ++ks) {
                #pragma unroll
                for (int nt = 0; nt < 4; ++nt) bb[nt] = hv[(nt * 4 + ks) * 64 + l];
                #pragma unroll
                for (int nt = 0; nt < 4; ++nt) {
                    acc2[0][nt] = __builtin_amdgcn_mfma_f32_16x16x32_bf16(W2r[ks][0], bb[nt], acc2[0][nt], 0, 0, 0);
                    acc2[1][nt] = __builtin_amdgcn_mfma_f32_16x16x32_bf16(W2r[ks][1], bb[nt], acc2[1][nt], 0, 0, 0);
                }
            }
        }
        __builtin_amdgcn_s_setprio(0);

        // ---- stage next fij frags into s_fp (after GEMM2 issue; before B2) ----
        if (i < ATOMS - 1) {
            uint4 pk0, pk1;
            pk0.x = cvt_pk(fa[0].x, fa[0].y); pk0.y = cvt_pk(fa[1].x, fa[1].y);
            pk0.z = cvt_pk(fa[2].x, fa[2].y); pk0.w = cvt_pk(fa[3].x, fa[3].y);
            pk1.x = cvt_pk(fb[0].x, fb[0].y); pk1.y = cvt_pk(fb[1].x, fb[1].y);
            pk1.z = cvt_pk(fb[2].x, fb[2].y); pk1.w = cvt_pk(fb[3].x, fb[3].y);
            *(uint4*)(&s_fp[((w * 2 + 0) * 64 + l) * 8]) = pk0;
            *(uint4*)(&s_fp[((w * 2 + 1) * 64 + l) * 8]) = pk1;
        }

        // ---- reduce over m: filter * mask * x, swizzle-butterfly, store ----
        #pragma unroll
        for (int f2 = 0; f2 < 2; ++f2) {
            float p0 = 0.f, p1 = 0.f, p2 = 0.f, p3 = 0.f;
            #pragma unroll
            for (int nt = 0; nt < 4; ++nt) {
                const float msk = mkv[nt];
                const uint2 xv = xg[f2][nt];
                const float x0 = __uint_as_float(xv.x << 16);
                const float x1 = __uint_as_float(xv.x & 0xffff0000u);
                const float x2 = __uint_as_float(xv.y << 16);
                const float x3 = __uint_as_float(xv.y & 0xffff0000u);
                p0 = fmaf(msk * acc2[f2][nt][0], x0, p0);
                p1 = fmaf(msk * acc2[f2][nt][1], x1, p1);
                p2 = fmaf(msk * acc2[f2][nt][2], x2, p2);
                p3 = fmaf(msk * acc2[f2][nt][3], x3, p3);
            }
            p0 = red16(p0); p1 = red16(p1); p2 = red16(p2); p3 = red16(p3);
            if (l16 == 0)
                *(float4*)(Y + (size_t)ba * F_ + 16 * (2 * w + f2) + 4 * q) = float4{p0, p1, p2, p3};
        }

        // ---- roll inputs; issue next xg gathers ----
        if (i < ATOMS - 1) {
            #pragma unroll
            for (int nt = 0; nt < 4; ++nt) { nbv[nt] = nbv2[nt]; mkv[nt] = mkv2[nt]; }
            #pragma unroll
            for (int f2 = 0; f2 < 2; ++f2)
                #pragma unroll
                for (int nt = 0; nt < 4; ++nt)
                    xg[f2][nt] = *(const uint2*)(xt_b + nbv[nt] * F_ + xoff + 16 * f2);
        }
        __syncthreads();   // B2: s_fp staged for i+1; H reads done
    }
}

extern "C" void kernel_launch(void* const* d_in, const int* in_sizes, int n_in,
                              void* d_out, int out_size, void* d_ws, size_t ws_size,
                              hipStream_t stream) {
    const float* x     = (const float*)d_in[0];
    const float* mask  = (const float*)d_in[1];
    const int*   nbr   = (const int*)d_in[2];
    const float* fij   = (const float*)d_in[3];
    const float* Wf1   = (const float*)d_in[4];
    const float* bf1   = (const float*)d_in[5];
    const float* Wf2   = (const float*)d_in[6];
    const float* bf2   = (const float*)d_in[7];
    const float* Win2f = (const float*)d_in[8];
    const float* Wout  = (const float*)d_in[9];
    const float* bout  = (const float*)d_in[10];
    float* out = (float*)d_out;

    char* ws = (char*)d_ws;
    unsigned short* W1p   = (unsigned short*)(ws);            // 16 KB
    unsigned short* W2p   = (unsigned short*)(ws + 16384);    // 32 KB
    unsigned short* Winp  = (unsigned short*)(ws + 49152);    // 32 KB
    unsigned short* Woutp = (unsigned short*)(ws + 81920);    // 32 KB
    unsigned short* xt    = (unsigned short*)(ws + 114688);   // 2 MB

    pack_all<<<224, 256, 0, stream>>>(Wf1, bf1, Wf2, Win2f, Wout, W1p, W2p, Winp, Woutp);

    rowgemm_kernel<false, true><<<B_ * A_ / 16, 64, 0, stream>>>(x, Winp, nullptr, xt);

    cfconv_main<<<B_ * A_ / ATOMS, 256, 0, stream>>>(xt, mask, nbr, fij, W1p, W2p, bf2, out);

    rowgemm_kernel<true, false><<<B_ * A_ / 16, 64, 0, stream>>>(out, Woutp, bout, out);
}

// Round 8
// 109.103 us; speedup vs baseline: 1.5503x; 1.3550x over previous
//
#include <hip/hip_runtime.h>

#define B_ 8
#define A_ 1024
#define N_ 64
#define G_ 50
#define F_ 128
#define ATOMS 4

typedef __attribute__((ext_vector_type(8))) short bf16x8;
typedef __attribute__((ext_vector_type(4))) float f32x4;

// cheap shifted-softplus: inputs bounded (|v| << 80), no stability split needed.
__device__ __forceinline__ float sspf(float v) {
    return __logf(1.f + __expf(v)) - 0.69314718055994530942f;
}
__device__ __forceinline__ unsigned short f2bf(float f) {
    unsigned u = __float_as_uint(f);
    u += 0x7fffu + ((u >> 16) & 1u);
    return (unsigned short)(u >> 16);
}
__device__ __forceinline__ unsigned cvt_pk(float lo, float hi) {
    unsigned r;
    asm("v_cvt_pk_bf16_f32 %0, %1, %2" : "=v"(r) : "v"(lo), "v"(hi));
    return r;
}
// butterfly sum over l16 (xor 1,2,4,8) via ds_swizzle immediates
__device__ __forceinline__ float red16(float p) {
    p += __int_as_float(__builtin_amdgcn_ds_swizzle(__float_as_int(p), 0x041F));
    p += __int_as_float(__builtin_amdgcn_ds_swizzle(__float_as_int(p), 0x081F));
    p += __int_as_float(__builtin_amdgcn_ds_swizzle(__float_as_int(p), 0x101F));
    p += __int_as_float(__builtin_amdgcn_ds_swizzle(__float_as_int(p), 0x201F));
    return p;
}

// Pack all four [K x 128] weights into MFMA fragment order:
// P[((ks*8+nt)*64+lane)*8+i] = W[(32ks+8*(lane>>4)+i)*128 + 16nt+(lane&15)]
// For W1 (K=50), row k==50 holds b_f1 (bias folded via f_ij pad element = 1).
__global__ __launch_bounds__(256) void pack_all(
    const float* __restrict__ W1, const float* __restrict__ b1,
    const float* __restrict__ W2, const float* __restrict__ Wi,
    const float* __restrict__ Wo,
    unsigned short* __restrict__ P1, unsigned short* __restrict__ P2,
    unsigned short* __restrict__ Pi, unsigned short* __restrict__ Po)
{
    int blk = blockIdx.x;
    const float* W; const float* bias = nullptr; unsigned short* P; int K, id;
    if (blk < 32)       { W = W1; P = P1; K = 50;  id = blk * 256 + threadIdx.x; bias = b1; }
    else if (blk < 96)  { W = W2; P = P2; K = 128; id = (blk - 32) * 256 + threadIdx.x; }
    else if (blk < 160) { W = Wi; P = Pi; K = 128; id = (blk - 96) * 256 + threadIdx.x; }
    else                { W = Wo; P = Po; K = 128; id = (blk - 160) * 256 + threadIdx.x; }
    int i    = id & 7;
    int lane = (id >> 3) & 63;
    int nt   = (id >> 9) & 7;
    int ks   = id >> 12;
    int k = 32 * ks + 8 * (lane >> 4) + i;
    int f = 16 * nt + (lane & 15);
    float v = (k < K) ? W[k * F_ + f] : ((bias && k == K) ? bias[f] : 0.f);
    P[id] = f2bf(v);
}

// out[R x 128] = (ACT? ssp : id)(A[R x 128] @ Bpacked + bias). 1 wave per 16 rows.
template <bool ACT, bool OUT_BF16>
__global__ __launch_bounds__(64) void rowgemm_kernel(
    const float* Afp, const unsigned short* __restrict__ Bp,
    const float* __restrict__ bias, void* outv)
{
    const int l  = threadIdx.x;
    const int r0 = blockIdx.x * 16;
    const bf16x8* Bv = (const bf16x8*)Bp;

    f32x4 acc[8];
    #pragma unroll
    for (int nt = 0; nt < 8; ++nt) acc[nt] = f32x4{0.f, 0.f, 0.f, 0.f};

    const int arow = r0 + (l & 15);
    const int koff = (l >> 4) * 8;
    #pragma unroll
    for (int ks = 0; ks < 4; ++ks) {
        const float* ap = Afp + (size_t)arow * F_ + ks * 32 + koff;
        float4 a0 = *(const float4*)ap;
        float4 a1 = *(const float4*)(ap + 4);
        bf16x8 af;
        af[0] = (short)f2bf(a0.x); af[1] = (short)f2bf(a0.y);
        af[2] = (short)f2bf(a0.z); af[3] = (short)f2bf(a0.w);
        af[4] = (short)f2bf(a1.x); af[5] = (short)f2bf(a1.y);
        af[6] = (short)f2bf(a1.z); af[7] = (short)f2bf(a1.w);
        #pragma unroll
        for (int nt = 0; nt < 8; ++nt) {
            bf16x8 bf = Bv[(ks * 8 + nt) * 64 + l];
            acc[nt] = __builtin_amdgcn_mfma_f32_16x16x32_bf16(af, bf, acc[nt], 0, 0, 0);
        }
    }
    #pragma unroll
    for (int nt = 0; nt < 8; ++nt) {
        int f = nt * 16 + (l & 15);
        float bv = bias ? bias[f] : 0.f;
        #pragma unroll
        for (int r = 0; r < 4; ++r) {
            int orow = r0 + (l >> 4) * 4 + r;
            float v = acc[nt][r] + bv;
            if (ACT) v = sspf(v);
            if (OUT_BF16) ((unsigned short*)outv)[(size_t)orow * F_ + f] = f2bf(v);
            else          ((float*)outv)[(size_t)orow * F_ + f] = v;
        }
    }
}

// 4 atoms/block, software-pipelined, single fij buffer (24 KB LDS), no reg cap poison.
__global__ __launch_bounds__(256, 3) void cfconv_main(
    const unsigned short* __restrict__ xt,   // [B*A][F] bf16
    const float* __restrict__ mask,          // [B,A,N]
    const int*   __restrict__ nbr,           // [B,A,N]
    const float* __restrict__ fij,           // [B,A,N,G]
    const unsigned short* __restrict__ W1s,  // packed, K=50 (+bias row 50)
    const unsigned short* __restrict__ W2s,  // packed, K=128
    const float* __restrict__ bf2,
    float* __restrict__ Y)                   // [B*A][F] pre-output
{
    const int bid = blockIdx.x;
    const int swz = (bid & 7) * (2048 / 8) + (bid >> 3);   // XCD-bijective (2048%8==0)
    const int ba0 = swz * ATOMS;
    const int t   = threadIdx.x;
    const int w   = t >> 6;
    const int l   = t & 63;
    const int l16 = l & 15;
    const int q   = l >> 4;

    __shared__ unsigned short s_fp[4096];   // fij frags, 8 KB (single buffer)
    __shared__ unsigned short s_hp[8192];   // H frags, 16 KB

    // ---- uniform bases (SADDR-form addressing) ----
    const unsigned short* xt_b = xt + ((size_t)(ba0 >> 10) << 10) * F_;  // this block's b
    const int xoff = 32 * w + 4 * q;        // f2=0 feature offset; f2=1 adds 16

    // ---- W fragments resident for the whole block ----
    const bf16x8* w1v = (const bf16x8*)W1s;
    const bf16x8* w2v = (const bf16x8*)W2s;
    bf16x8 W1r[2][2], W2r[4][2];
    #pragma unroll
    for (int ks = 0; ks < 2; ++ks) {
        W1r[ks][0] = w1v[(ks * 8 + 2 * w + 0) * 64 + l];
        W1r[ks][1] = w1v[(ks * 8 + 2 * w + 1) * 64 + l];
    }
    #pragma unroll
    for (int ks = 0; ks < 4; ++ks) {
        W2r[ks][0] = w2v[(ks * 8 + 2 * w + 0) * 64 + l];
        W2r[ks][1] = w2v[(ks * 8 + 2 * w + 1) * 64 + l];
    }
    f32x4 b2acc[2];
    {
        float4 t0 = *(const float4*)(bf2 + 16 * (2 * w + 0) + 4 * q);
        float4 t1 = *(const float4*)(bf2 + 16 * (2 * w + 1) + 4 * q);
        b2acc[0] = f32x4{t0.x, t0.y, t0.z, t0.w};
        b2acc[1] = f32x4{t1.x, t1.y, t1.z, t1.w};
    }

    // ---- prologue: atom 0 inputs ----
    int nbv[4]; float mkv[4];
    {
        const int*   nb0 = nbr  + (size_t)ba0 * N_;
        const float* mk0 = mask + (size_t)ba0 * N_;
        #pragma unroll
        for (int nt = 0; nt < 4; ++nt) {
            nbv[nt] = nb0[16 * nt + l16];
            mkv[nt] = mk0[16 * nt + l16];
        }
    }
    float2 fa[4], fb[4];
    {
        const float* frow = fij + (size_t)ba0 * (N_ * G_) + (16 * w + l16) * G_;
        #pragma unroll
        for (int j = 0; j < 4; ++j) fa[j] = *(const float2*)(frow + 8 * q + 2 * j);
        if (q < 2) {
            #pragma unroll
            for (int j = 0; j < 4; ++j) fb[j] = *(const float2*)(frow + 32 + 8 * q + 2 * j);
        } else if (q == 2) {
            fb[0] = *(const float2*)(frow + 48);
            fb[1] = float2{1.f, 0.f};  // g=50: bias row of W1
            fb[2] = float2{0.f, 0.f}; fb[3] = float2{0.f, 0.f};
        } else {
            #pragma unroll
            for (int j = 0; j < 4; ++j) fb[j] = float2{0.f, 0.f};
        }
    }
    uint2 xg[2][4];
    #pragma unroll
    for (int f2 = 0; f2 < 2; ++f2)
        #pragma unroll
        for (int nt = 0; nt < 4; ++nt)
            xg[f2][nt] = *(const uint2*)(xt_b + nbv[nt] * F_ + xoff + 16 * f2);
    {
        uint4 pk0, pk1;
        pk0.x = cvt_pk(fa[0].x, fa[0].y); pk0.y = cvt_pk(fa[1].x, fa[1].y);
        pk0.z = cvt_pk(fa[2].x, fa[2].y); pk0.w = cvt_pk(fa[3].x, fa[3].y);
        pk1.x = cvt_pk(fb[0].x, fb[0].y); pk1.y = cvt_pk(fb[1].x, fb[1].y);
        pk1.z = cvt_pk(fb[2].x, fb[2].y); pk1.w = cvt_pk(fb[3].x, fb[3].y);
        *(uint4*)(&s_fp[((w * 2 + 0) * 64 + l) * 8]) = pk0;
        *(uint4*)(&s_fp[((w * 2 + 1) * 64 + l) * 8]) = pk1;
    }
    __syncthreads();

    int nbv2[4]; float mkv2[4];

    #pragma unroll
    for (int i = 0; i < ATOMS; ++i) {
        const int ba = ba0 + i;

        // ---- issue next atom's fij + nbr/mask FIRST (max latency cover) ----
        if (i < ATOMS - 1) {
            const float* frow = fij + (size_t)(ba + 1) * (N_ * G_) + (16 * w + l16) * G_;
            #pragma unroll
            for (int j = 0; j < 4; ++j) fa[j] = *(const float2*)(frow + 8 * q + 2 * j);
            if (q < 2) {
                #pragma unroll
                for (int j = 0; j < 4; ++j) fb[j] = *(const float2*)(frow + 32 + 8 * q + 2 * j);
            } else if (q == 2) {
                fb[0] = *(const float2*)(frow + 48);
                fb[1] = float2{1.f, 0.f};
                fb[2] = float2{0.f, 0.f}; fb[3] = float2{0.f, 0.f};
            } else {
                #pragma unroll
                for (int j = 0; j < 4; ++j) fb[j] = float2{0.f, 0.f};
            }
            const int*   nb1 = nbr  + (size_t)(ba + 1) * N_;
            const float* mk1 = mask + (size_t)(ba + 1) * N_;
            #pragma unroll
            for (int nt = 0; nt < 4; ++nt) {
                nbv2[nt] = nb1[16 * nt + l16];
                mkv2[nt] = mk1[16 * nt + l16];
            }
        }

        // ---- GEMM1 (ks=0 peeled with zero C): acc1[ct2][nt] ----
        const bf16x8* fv = (const bf16x8*)s_fp;
        f32x4 acc1[2][4];
        __builtin_amdgcn_s_setprio(1);
        {
            bf16x8 bb[4];
            #pragma unroll
            for (int nt = 0; nt < 4; ++nt) bb[nt] = fv[(nt * 2 + 0) * 64 + l];
            #pragma unroll
            for (int nt = 0; nt < 4; ++nt) {
                acc1[0][nt] = __builtin_amdgcn_mfma_f32_16x16x32_bf16(W1r[0][0], bb[nt], f32x4{0.f,0.f,0.f,0.f}, 0, 0, 0);
                acc1[1][nt] = __builtin_amdgcn_mfma_f32_16x16x32_bf16(W1r[0][1], bb[nt], f32x4{0.f,0.f,0.f,0.f}, 0, 0, 0);
            }
            #pragma unroll
            for (int nt = 0; nt < 4; ++nt) bb[nt] = fv[(nt * 2 + 1) * 64 + l];
            #pragma unroll
            for (int nt = 0; nt < 4; ++nt) {
                acc1[0][nt] = __builtin_amdgcn_mfma_f32_16x16x32_bf16(W1r[1][0], bb[nt], acc1[0][nt], 0, 0, 0);
                acc1[1][nt] = __builtin_amdgcn_mfma_f32_16x16x32_bf16(W1r[1][1], bb[nt], acc1[1][nt], 0, 0, 0);
            }
        }
        __builtin_amdgcn_s_setprio(0);

        // ---- H epilogue: ssp -> B-frag layout (bias pre-folded via pad row) ----
        #pragma unroll
        for (int ct2 = 0; ct2 < 2; ++ct2) {
            const int addr = ((w * 64 + 16 * (2 * ct2 + (q >> 1)) + l16) * 8 + 4 * (q & 1));
            #pragma unroll
            for (int nt = 0; nt < 4; ++nt) {
                float h0 = sspf(acc1[ct2][nt][0]);
                float h1 = sspf(acc1[ct2][nt][1]);
                float h2 = sspf(acc1[ct2][nt][2]);
                float h3 = sspf(acc1[ct2][nt][3]);
                uint2 pk;
                pk.x = cvt_pk(h0, h1);
                pk.y = cvt_pk(h2, h3);
                *(uint2*)(&s_hp[nt * 2048 + addr]) = pk;
            }
        }
        __syncthreads();   // B1: fij reads done AND H frags ready

        // ---- GEMM2 (ks=0 peeled with C = bias2): acc2[f2][nt] ----
        const bf16x8* hv = (const bf16x8*)s_hp;
        f32x4 acc2[2][4];
        __builtin_amdgcn_s_setprio(1);
        {
            bf16x8 bb[4];
            #pragma unroll
            for (int nt = 0; nt < 4; ++nt) bb[nt] = hv[(nt * 4 + 0) * 64 + l];
            #pragma unroll
            for (int nt = 0; nt < 4; ++nt) {
                acc2[0][nt] = __builtin_amdgcn_mfma_f32_16x16x32_bf16(W2r[0][0], bb[nt], b2acc[0], 0, 0, 0);
                acc2[1][nt] = __builtin_amdgcn_mfma_f32_16x16x32_bf16(W2r[0][1], bb[nt], b2acc[1], 0, 0, 0);
            }
            #pragma unroll
            for (int ks = 1; ks < 4; ++ks) {
                #pragma unroll
                for (int nt = 0; nt < 4; ++nt) bb[nt] = hv[(nt * 4 + ks) * 64 + l];
                #pragma unroll
                for (int nt = 0; nt < 4; ++nt) {
                    acc2[0][nt] = __builtin_amdgcn_mfma_f32_16x16x32_bf16(W2r[ks][0], bb[nt], acc2[0][nt], 0, 0, 0);
                    acc2[1][nt] = __builtin_amdgcn_mfma_f32_16x16x32_bf16(W2r[ks][1], bb[nt], acc2[1][nt], 0, 0, 0);
                }
            }
        }
        __builtin_amdgcn_s_setprio(0);

        // ---- stage next fij frags into s_fp (after GEMM2 issue; before B2) ----
        if (i < ATOMS - 1) {
            uint4 pk0, pk1;
            pk0.x = cvt_pk(fa[0].x, fa[0].y); pk0.y = cvt_pk(fa[1].x, fa[1].y);
            pk0.z = cvt_pk(fa[2].x, fa[2].y); pk0.w = cvt_pk(fa[3].x, fa[3].y);
            pk1.x = cvt_pk(fb[0].x, fb[0].y); pk1.y = cvt_pk(fb[1].x, fb[1].y);
            pk1.z = cvt_pk(fb[2].x, fb[2].y); pk1.w = cvt_pk(fb[3].x, fb[3].y);
            *(uint4*)(&s_fp[((w * 2 + 0) * 64 + l) * 8]) = pk0;
            *(uint4*)(&s_fp[((w * 2 + 1) * 64 + l) * 8]) = pk1;
        }

        // ---- reduce over m: filter * mask * x, swizzle-butterfly, store ----
        #pragma unroll
        for (int f2 = 0; f2 < 2; ++f2) {
            float p0 = 0.f, p1 = 0.f, p2 = 0.f, p3 = 0.f;
            #pragma unroll
            for (int nt = 0; nt < 4; ++nt) {
                const float msk = mkv[nt];
                const uint2 xv = xg[f2][nt];
                const float x0 = __uint_as_float(xv.x << 16);
                const float x1 = __uint_as_float(xv.x & 0xffff0000u);
                const float x2 = __uint_as_float(xv.y << 16);
                const float x3 = __uint_as_float(xv.y & 0xffff0000u);
                p0 = fmaf(msk * acc2[f2][nt][0], x0, p0);
                p1 = fmaf(msk * acc2[f2][nt][1], x1, p1);
                p2 = fmaf(msk * acc2[f2][nt][2], x2, p2);
                p3 = fmaf(msk * acc2[f2][nt][3], x3, p3);
            }
            p0 = red16(p0); p1 = red16(p1); p2 = red16(p2); p3 = red16(p3);
            if (l16 == 0)
                *(float4*)(Y + (size_t)ba * F_ + 16 * (2 * w + f2) + 4 * q) = float4{p0, p1, p2, p3};
        }

        // ---- roll inputs; issue next xg gathers ----
        if (i < ATOMS - 1) {
            #pragma unroll
            for (int nt = 0; nt < 4; ++nt) { nbv[nt] = nbv2[nt]; mkv[nt] = mkv2[nt]; }
            #pragma unroll
            for (int f2 = 0; f2 < 2; ++f2)
                #pragma unroll
                for (int nt = 0; nt < 4; ++nt)
                    xg[f2][nt] = *(const uint2*)(xt_b + nbv[nt] * F_ + xoff + 16 * f2);
        }
        __syncthreads();   // B2: s_fp staged for i+1; H reads done
    }
}

extern "C" void kernel_launch(void* const* d_in, const int* in_sizes, int n_in,
                              void* d_out, int out_size, void* d_ws, size_t ws_size,
                              hipStream_t stream) {
    const float* x     = (const float*)d_in[0];
    const float* mask  = (const float*)d_in[1];
    const int*   nbr   = (const int*)d_in[2];
    const float* fij   = (const float*)d_in[3];
    const float* Wf1   = (const float*)d_in[4];
    const float* bf1   = (const float*)d_in[5];
    const float* Wf2   = (const float*)d_in[6];
    const float* bf2   = (const float*)d_in[7];
    const float* Win2f = (const float*)d_in[8];
    const float* Wout  = (const float*)d_in[9];
    const float* bout  = (const float*)d_in[10];
    float* out = (float*)d_out;

    char* ws = (char*)d_ws;
    unsigned short* W1p   = (unsigned short*)(ws);            // 16 KB
    unsigned short* W2p   = (unsigned short*)(ws + 16384);    // 32 KB
    unsigned short* Winp  = (unsigned short*)(ws + 49152);    // 32 KB
    unsigned short* Woutp = (unsigned short*)(ws + 81920);    // 32 KB
    unsigned short* xt    = (unsigned short*)(ws + 114688);   // 2 MB

    pack_all<<<224, 256, 0, stream>>>(Wf1, bf1, Wf2, Win2f, Wout, W1p, W2p, Winp, Woutp);

    rowgemm_kernel<false, true><<<B_ * A_ / 16, 64, 0, stream>>>(x, Winp, nullptr, xt);

    cfconv_main<<<B_ * A_ / ATOMS, 256, 0, stream>>>(xt, mask, nbr, fij, W1p, W2p, bf2, out);

    rowgemm_kernel<true, false><<<B_ * A_ / 16, 64, 0, stream>>>(out, Woutp, bout, out);
}

// Round 9
// 86.377 us; speedup vs baseline: 1.9582x; 1.2631x over previous
//
#include <hip/hip_runtime.h>

#define B_ 8
#define A_ 1024
#define N_ 64
#define G_ 50
#define F_ 128
#define ATOMS 4

typedef __attribute__((ext_vector_type(8))) short bf16x8;
typedef __attribute__((ext_vector_type(4))) float f32x4;

// cheap shifted-softplus: pre-activations bounded far from fp32 overflow.
__device__ __forceinline__ float sspf(float v) {
    return __logf(1.f + __expf(v)) - 0.69314718055994530942f;
}
__device__ __forceinline__ unsigned short f2bf(float f) {
    unsigned u = __float_as_uint(f);
    u += 0x7fffu + ((u >> 16) & 1u);
    return (unsigned short)(u >> 16);
}
__device__ __forceinline__ unsigned cvt_pk(float lo, float hi) {
    unsigned r;
    asm("v_cvt_pk_bf16_f32 %0, %1, %2" : "=v"(r) : "v"(lo), "v"(hi));
    return r;
}
// butterfly sum over l16 (xor 1,2,4,8) via ds_swizzle immediates
__device__ __forceinline__ float red16(float p) {
    p += __int_as_float(__builtin_amdgcn_ds_swizzle(__float_as_int(p), 0x041F));
    p += __int_as_float(__builtin_amdgcn_ds_swizzle(__float_as_int(p), 0x081F));
    p += __int_as_float(__builtin_amdgcn_ds_swizzle(__float_as_int(p), 0x101F));
    p += __int_as_float(__builtin_amdgcn_ds_swizzle(__float_as_int(p), 0x201F));
    return p;
}

// Pack all four [K x 128] weights into MFMA fragment order:
// P[((ks*8+nt)*64+lane)*8+i] = W[(32ks+8*(lane>>4)+i)*128 + 16nt+(lane&15)]
// For W1 (K=50), row k==50 holds b_f1 (bias folded via f_ij pad element = 1).
__global__ __launch_bounds__(256) void pack_all(
    const float* __restrict__ W1, const float* __restrict__ b1,
    const float* __restrict__ W2, const float* __restrict__ Wi,
    const float* __restrict__ Wo,
    unsigned short* __restrict__ P1, unsigned short* __restrict__ P2,
    unsigned short* __restrict__ Pi, unsigned short* __restrict__ Po)
{
    int blk = blockIdx.x;
    const float* W; const float* bias = nullptr; unsigned short* P; int K, id;
    if (blk < 32)       { W = W1; P = P1; K = 50;  id = blk * 256 + threadIdx.x; bias = b1; }
    else if (blk < 96)  { W = W2; P = P2; K = 128; id = (blk - 32) * 256 + threadIdx.x; }
    else if (blk < 160) { W = Wi; P = Pi; K = 128; id = (blk - 96) * 256 + threadIdx.x; }
    else                { W = Wo; P = Po; K = 128; id = (blk - 160) * 256 + threadIdx.x; }
    int i    = id & 7;
    int lane = (id >> 3) & 63;
    int nt   = (id >> 9) & 7;
    int ks   = id >> 12;
    int k = 32 * ks + 8 * (lane >> 4) + i;
    int f = 16 * nt + (lane & 15);
    float v = (k < K) ? W[k * F_ + f] : ((bias && k == K) ? bias[f] : 0.f);
    P[id] = f2bf(v);
}

// out[R x 128] = (ACT? ssp : id)(A[R x 128] @ Bpacked + bias). 1 wave per 16 rows.
template <bool ACT, bool OUT_BF16>
__global__ __launch_bounds__(64) void rowgemm_kernel(
    const float* Afp, const unsigned short* __restrict__ Bp,
    const float* __restrict__ bias, void* outv)
{
    const int l  = threadIdx.x;
    const int r0 = blockIdx.x * 16;
    const bf16x8* Bv = (const bf16x8*)Bp;

    f32x4 acc[8];
    #pragma unroll
    for (int nt = 0; nt < 8; ++nt) acc[nt] = f32x4{0.f, 0.f, 0.f, 0.f};

    const int arow = r0 + (l & 15);
    const int koff = (l >> 4) * 8;
    #pragma unroll
    for (int ks = 0; ks < 4; ++ks) {
        const float* ap = Afp + (size_t)arow * F_ + ks * 32 + koff;
        float4 a0 = *(const float4*)ap;
        float4 a1 = *(const float4*)(ap + 4);
        bf16x8 af;
        af[0] = (short)f2bf(a0.x); af[1] = (short)f2bf(a0.y);
        af[2] = (short)f2bf(a0.z); af[3] = (short)f2bf(a0.w);
        af[4] = (short)f2bf(a1.x); af[5] = (short)f2bf(a1.y);
        af[6] = (short)f2bf(a1.z); af[7] = (short)f2bf(a1.w);
        #pragma unroll
        for (int nt = 0; nt < 8; ++nt) {
            bf16x8 bf = Bv[(ks * 8 + nt) * 64 + l];
            acc[nt] = __builtin_amdgcn_mfma_f32_16x16x32_bf16(af, bf, acc[nt], 0, 0, 0);
        }
    }
    #pragma unroll
    for (int nt = 0; nt < 8; ++nt) {
        int f = nt * 16 + (l & 15);
        float bv = bias ? bias[f] : 0.f;
        #pragma unroll
        for (int r = 0; r < 4; ++r) {
            int orow = r0 + (l >> 4) * 4 + r;
            float v = acc[nt][r] + bv;
            if (ACT) v = sspf(v);
            if (OUT_BF16) ((unsigned short*)outv)[(size_t)orow * F_ + f] = f2bf(v);
            else          ((float*)outv)[(size_t)orow * F_ + f] = v;
        }
    }
}

// 4 atoms/block, r5 pipeline ordering (short live ranges), double-buffered fij.
__global__ __launch_bounds__(256, 3) void cfconv_main(
    const unsigned short* __restrict__ xt,   // [B*A][F] bf16
    const float* __restrict__ mask,          // [B,A,N]
    const int*   __restrict__ nbr,           // [B,A,N]
    const float* __restrict__ fij,           // [B,A,N,G]
    const unsigned short* __restrict__ W1s,  // packed, K=50 (+bias row 50)
    const unsigned short* __restrict__ W2s,  // packed, K=128
    const float* __restrict__ bf2,
    float* __restrict__ Y)                   // [B*A][F] pre-output
{
    const int bid = blockIdx.x;
    const int swz = (bid & 7) * (2048 / 8) + (bid >> 3);   // XCD-bijective (2048%8==0)
    const int ba0 = swz * ATOMS;
    const int t   = threadIdx.x;
    const int w   = t >> 6;
    const int l   = t & 63;
    const int l16 = l & 15;
    const int q   = l >> 4;

    __shared__ unsigned short s_fp[2][4096];  // fij frags, double-buffered, 8KB each
    __shared__ unsigned short s_hp[8192];     // H frags, 16 KB

    // ---- uniform base for gathers (SADDR form) ----
    const unsigned short* xt_b = xt + ((size_t)(ba0 >> 10) << 10) * F_;
    const int xoff = 32 * w + 4 * q;

    // ---- W fragments + bias resident for the whole block ----
    const bf16x8* w1v = (const bf16x8*)W1s;
    const bf16x8* w2v = (const bf16x8*)W2s;
    bf16x8 W1r[2][2], W2r[4][2];
    #pragma unroll
    for (int ks = 0; ks < 2; ++ks) {
        W1r[ks][0] = w1v[(ks * 8 + 2 * w + 0) * 64 + l];
        W1r[ks][1] = w1v[(ks * 8 + 2 * w + 1) * 64 + l];
    }
    #pragma unroll
    for (int ks = 0; ks < 4; ++ks) {
        W2r[ks][0] = w2v[(ks * 8 + 2 * w + 0) * 64 + l];
        W2r[ks][1] = w2v[(ks * 8 + 2 * w + 1) * 64 + l];
    }
    f32x4 b2acc[2];
    {
        float4 t0 = *(const float4*)(bf2 + 16 * (2 * w + 0) + 4 * q);
        float4 t1 = *(const float4*)(bf2 + 16 * (2 * w + 1) + 4 * q);
        b2acc[0] = f32x4{t0.x, t0.y, t0.z, t0.w};
        b2acc[1] = f32x4{t1.x, t1.y, t1.z, t1.w};
    }

    // ---- prologue: atom 0 inputs ----
    int nbv[4]; float mkv[4];
    {
        const int*   nb0 = nbr  + (size_t)ba0 * N_;
        const float* mk0 = mask + (size_t)ba0 * N_;
        #pragma unroll
        for (int nt = 0; nt < 4; ++nt) {
            nbv[nt] = nb0[16 * nt + l16];
            mkv[nt] = mk0[16 * nt + l16];
        }
    }
    float2 fa[4], fb[4];
    {
        const float* frow = fij + (size_t)ba0 * (N_ * G_) + (16 * w + l16) * G_;
        #pragma unroll
        for (int j = 0; j < 4; ++j) fa[j] = *(const float2*)(frow + 8 * q + 2 * j);
        if (q < 2) {
            #pragma unroll
            for (int j = 0; j < 4; ++j) fb[j] = *(const float2*)(frow + 32 + 8 * q + 2 * j);
        } else if (q == 2) {
            fb[0] = *(const float2*)(frow + 48);
            fb[1] = float2{1.f, 0.f};  // g=50: bias row of W1
            fb[2] = float2{0.f, 0.f}; fb[3] = float2{0.f, 0.f};
        } else {
            #pragma unroll
            for (int j = 0; j < 4; ++j) fb[j] = float2{0.f, 0.f};
        }
    }
    uint2 xg[2][4];
    #pragma unroll
    for (int f2 = 0; f2 < 2; ++f2)
        #pragma unroll
        for (int nt = 0; nt < 4; ++nt)
            xg[f2][nt] = *(const uint2*)(xt_b + nbv[nt] * F_ + xoff + 16 * f2);
    {
        uint4 pk0, pk1;
        pk0.x = cvt_pk(fa[0].x, fa[0].y); pk0.y = cvt_pk(fa[1].x, fa[1].y);
        pk0.z = cvt_pk(fa[2].x, fa[2].y); pk0.w = cvt_pk(fa[3].x, fa[3].y);
        pk1.x = cvt_pk(fb[0].x, fb[0].y); pk1.y = cvt_pk(fb[1].x, fb[1].y);
        pk1.z = cvt_pk(fb[2].x, fb[2].y); pk1.w = cvt_pk(fb[3].x, fb[3].y);
        *(uint4*)(&s_fp[0][((w * 2 + 0) * 64 + l) * 8]) = pk0;
        *(uint4*)(&s_fp[0][((w * 2 + 1) * 64 + l) * 8]) = pk1;
    }
    __syncthreads();

    int nbv2[4]; float mkv2[4];

    #pragma unroll
    for (int i = 0; i < ATOMS; ++i) {
        const int ba = ba0 + i;
        const unsigned short* fp_cur = s_fp[i & 1];
        unsigned short* fp_nxt = s_fp[(i + 1) & 1];

        // ---- GEMM1 (ks=0 peeled with zero C): acc1[ct2][nt] ----
        const bf16x8* fv = (const bf16x8*)fp_cur;
        f32x4 acc1[2][4];
        __builtin_amdgcn_s_setprio(1);
        {
            bf16x8 bb[4];
            #pragma unroll
            for (int nt = 0; nt < 4; ++nt) bb[nt] = fv[(nt * 2 + 0) * 64 + l];
            #pragma unroll
            for (int nt = 0; nt < 4; ++nt) {
                acc1[0][nt] = __builtin_amdgcn_mfma_f32_16x16x32_bf16(W1r[0][0], bb[nt], f32x4{0.f,0.f,0.f,0.f}, 0, 0, 0);
                acc1[1][nt] = __builtin_amdgcn_mfma_f32_16x16x32_bf16(W1r[0][1], bb[nt], f32x4{0.f,0.f,0.f,0.f}, 0, 0, 0);
            }
            #pragma unroll
            for (int nt = 0; nt < 4; ++nt) bb[nt] = fv[(nt * 2 + 1) * 64 + l];
            #pragma unroll
            for (int nt = 0; nt < 4; ++nt) {
                acc1[0][nt] = __builtin_amdgcn_mfma_f32_16x16x32_bf16(W1r[1][0], bb[nt], acc1[0][nt], 0, 0, 0);
                acc1[1][nt] = __builtin_amdgcn_mfma_f32_16x16x32_bf16(W1r[1][1], bb[nt], acc1[1][nt], 0, 0, 0);
            }
        }
        __builtin_amdgcn_s_setprio(0);

        // ---- issue next atom's fij + nbr/mask (fly under epilogue; SHORT live range) ----
        if (i < ATOMS - 1) {
            const float* frow = fij + (size_t)(ba + 1) * (N_ * G_) + (16 * w + l16) * G_;
            #pragma unroll
            for (int j = 0; j < 4; ++j) fa[j] = *(const float2*)(frow + 8 * q + 2 * j);
            if (q < 2) {
                #pragma unroll
                for (int j = 0; j < 4; ++j) fb[j] = *(const float2*)(frow + 32 + 8 * q + 2 * j);
            } else if (q == 2) {
                fb[0] = *(const float2*)(frow + 48);
                fb[1] = float2{1.f, 0.f};
                fb[2] = float2{0.f, 0.f}; fb[3] = float2{0.f, 0.f};
            } else {
                #pragma unroll
                for (int j = 0; j < 4; ++j) fb[j] = float2{0.f, 0.f};
            }
            const int*   nb1 = nbr  + (size_t)(ba + 1) * N_;
            const float* mk1 = mask + (size_t)(ba + 1) * N_;
            #pragma unroll
            for (int nt = 0; nt < 4; ++nt) {
                nbv2[nt] = nb1[16 * nt + l16];
                mkv2[nt] = mk1[16 * nt + l16];
            }
        }

        // ---- H epilogue: ssp -> B-frag layout (bias pre-folded via pad row) ----
        #pragma unroll
        for (int ct2 = 0; ct2 < 2; ++ct2) {
            const int addr = ((w * 64 + 16 * (2 * ct2 + (q >> 1)) + l16) * 8 + 4 * (q & 1));
            #pragma unroll
            for (int nt = 0; nt < 4; ++nt) {
                float h0 = sspf(acc1[ct2][nt][0]);
                float h1 = sspf(acc1[ct2][nt][1]);
                float h2 = sspf(acc1[ct2][nt][2]);
                float h3 = sspf(acc1[ct2][nt][3]);
                uint2 pk;
                pk.x = cvt_pk(h0, h1);
                pk.y = cvt_pk(h2, h3);
                *(uint2*)(&s_hp[nt * 2048 + addr]) = pk;
            }
        }

        // ---- stage next fij frags into the OTHER buffer (consume fa/fb now) ----
        if (i < ATOMS - 1) {
            uint4 pk0, pk1;
            pk0.x = cvt_pk(fa[0].x, fa[0].y); pk0.y = cvt_pk(fa[1].x, fa[1].y);
            pk0.z = cvt_pk(fa[2].x, fa[2].y); pk0.w = cvt_pk(fa[3].x, fa[3].y);
            pk1.x = cvt_pk(fb[0].x, fb[0].y); pk1.y = cvt_pk(fb[1].x, fb[1].y);
            pk1.z = cvt_pk(fb[2].x, fb[2].y); pk1.w = cvt_pk(fb[3].x, fb[3].y);
            *(uint4*)(&fp_nxt[((w * 2 + 0) * 64 + l) * 8]) = pk0;
            *(uint4*)(&fp_nxt[((w * 2 + 1) * 64 + l) * 8]) = pk1;
        }
        __syncthreads();   // B1: H frags + next fij frags ready

        // ---- GEMM2 (ks=0 peeled with C = bias2): acc2[f2][nt] ----
        const bf16x8* hv = (const bf16x8*)s_hp;
        f32x4 acc2[2][4];
        __builtin_amdgcn_s_setprio(1);
        {
            bf16x8 bb[4];
            #pragma unroll
            for (int nt = 0; nt < 4; ++nt) bb[nt] = hv[(nt * 4 + 0) * 64 + l];
            #pragma unroll
            for (int nt = 0; nt < 4; ++nt) {
                acc2[0][nt] = __builtin_amdgcn_mfma_f32_16x16x32_bf16(W2r[0][0], bb[nt], b2acc[0], 0, 0, 0);
                acc2[1][nt] = __builtin_amdgcn_mfma_f32_16x16x32_bf16(W2r[0][1], bb[nt], b2acc[1], 0, 0, 0);
            }
            #pragma unroll
            for (int ks = 1; ks < 4; ++ks) {
                #pragma unroll
                for (int nt = 0; nt < 4; ++nt) bb[nt] = hv[(nt * 4 + ks) * 64 + l];
                #pragma unroll
                for (int nt = 0; nt < 4; ++nt) {
                    acc2[0][nt] = __builtin_amdgcn_mfma_f32_16x16x32_bf16(W2r[ks][0], bb[nt], acc2[0][nt], 0, 0, 0);
                    acc2[1][nt] = __builtin_amdgcn_mfma_f32_16x16x32_bf16(W2r[ks][1], bb[nt], acc2[1][nt], 0, 0, 0);
                }
            }
        }
        __builtin_amdgcn_s_setprio(0);

        // ---- reduce over m: filter * mask * x, swizzle-butterfly, store ----
        #pragma unroll
        for (int f2 = 0; f2 < 2; ++f2) {
            float p0 = 0.f, p1 = 0.f, p2 = 0.f, p3 = 0.f;
            #pragma unroll
            for (int nt = 0; nt < 4; ++nt) {
                const float msk = mkv[nt];
                const uint2 xv = xg[f2][nt];
                const float x0 = __uint_as_float(xv.x << 16);
                const float x1 = __uint_as_float(xv.x & 0xffff0000u);
                const float x2 = __uint_as_float(xv.y << 16);
                const float x3 = __uint_as_float(xv.y & 0xffff0000u);
                p0 = fmaf(msk * acc2[f2][nt][0], x0, p0);
                p1 = fmaf(msk * acc2[f2][nt][1], x1, p1);
                p2 = fmaf(msk * acc2[f2][nt][2], x2, p2);
                p3 = fmaf(msk * acc2[f2][nt][3], x3, p3);
            }
            p0 = red16(p0); p1 = red16(p1); p2 = red16(p2); p3 = red16(p3);
            if (l16 == 0)
                *(float4*)(Y + (size_t)ba * F_ + 16 * (2 * w + f2) + 4 * q) = float4{p0, p1, p2, p3};
        }

        // ---- roll inputs; issue next xg gathers (fly under next GEMM1+epilogue) ----
        if (i < ATOMS - 1) {
            #pragma unroll
            for (int nt = 0; nt < 4; ++nt) { nbv[nt] = nbv2[nt]; mkv[nt] = mkv2[nt]; }
            #pragma unroll
            for (int f2 = 0; f2 < 2; ++f2)
                #pragma unroll
                for (int nt = 0; nt < 4; ++nt)
                    xg[f2][nt] = *(const uint2*)(xt_b + nbv[nt] * F_ + xoff + 16 * f2);
        }
        __syncthreads();   // B2: H reads done; fp buffer for i+1 already staged
    }
}

extern "C" void kernel_launch(void* const* d_in, const int* in_sizes, int n_in,
                              void* d_out, int out_size, void* d_ws, size_t ws_size,
                              hipStream_t stream) {
    const float* x     = (const float*)d_in[0];
    const float* mask  = (const float*)d_in[1];
    const int*   nbr   = (const int*)d_in[2];
    const float* fij   = (const float*)d_in[3];
    const float* Wf1   = (const float*)d_in[4];
    const float* bf1   = (const float*)d_in[5];
    const float* Wf2   = (const float*)d_in[6];
    const float* bf2   = (const float*)d_in[7];
    const float* Win2f = (const float*)d_in[8];
    const float* Wout  = (const float*)d_in[9];
    const float* bout  = (const float*)d_in[10];
    float* out = (float*)d_out;

    char* ws = (char*)d_ws;
    unsigned short* W1p   = (unsigned short*)(ws);            // 16 KB
    unsigned short* W2p   = (unsigned short*)(ws + 16384);    // 32 KB
    unsigned short* Winp  = (unsigned short*)(ws + 49152);    // 32 KB
    unsigned short* Woutp = (unsigned short*)(ws + 81920);    // 32 KB
    unsigned short* xt    = (unsigned short*)(ws + 114688);   // 2 MB

    pack_all<<<224, 256, 0, stream>>>(Wf1, bf1, Wf2, Win2f, Wout, W1p, W2p, Winp, Woutp);

    rowgemm_kernel<false, true><<<B_ * A_ / 16, 64, 0, stream>>>(x, Winp, nullptr, xt);

    cfconv_main<<<B_ * A_ / ATOMS, 256, 0, stream>>>(xt, mask, nbr, fij, W1p, W2p, bf2, out);

    rowgemm_kernel<true, false><<<B_ * A_ / 16, 64, 0, stream>>>(out, Woutp, bout, out);
}

// Round 10
// 77.578 us; speedup vs baseline: 2.1803x; 1.1134x over previous
//
#include <hip/hip_runtime.h>

#define B_ 8
#define A_ 1024
#define N_ 64
#define G_ 50
#define F_ 128
#define ATOMS 4

typedef __attribute__((ext_vector_type(8))) short bf16x8;
typedef __attribute__((ext_vector_type(4))) float f32x4;

// exact ssp for the output kernel (pre-activations bounded, cheap form ok)
__device__ __forceinline__ float sspf(float v) {
    return __logf(1.f + __expf(v)) - 0.69314718055994530942f;
}
// scaled-domain ssp: inputs pre-scaled by log2e, output is ssp/ln2 (ln2 folded into W2)
__device__ __forceinline__ float ssp2(float v) {
    return __log2f(1.f + exp2f(v)) - 1.f;
}
__device__ __forceinline__ unsigned short f2bf(float f) {
    unsigned u = __float_as_uint(f);
    u += 0x7fffu + ((u >> 16) & 1u);
    return (unsigned short)(u >> 16);
}
__device__ __forceinline__ unsigned cvt_pk(float lo, float hi) {
    unsigned r;
    asm("v_cvt_pk_bf16_f32 %0, %1, %2" : "=v"(r) : "v"(lo), "v"(hi));
    return r;
}
// butterfly sum over l16 via DPP (no LDS): quad_perm xor1/xor2, half-mirror, mirror
template <int CTRL>
__device__ __forceinline__ float dppadd(float v) {
    int x = __builtin_amdgcn_mov_dpp(__float_as_int(v), CTRL, 0xF, 0xF, true);
    return v + __int_as_float(x);
}
__device__ __forceinline__ float red16(float p) {
    p = dppadd<0xB1>(p);    // xor 1 (quad_perm [1,0,3,2])
    p = dppadd<0x4E>(p);    // xor 2 (quad_perm [2,3,0,1])
    p = dppadd<0x141>(p);   // row_half_mirror (pairs across 4-boundary)
    p = dppadd<0x140>(p);   // row_mirror (pairs across 8-boundary)
    return p;
}

// Pack all four [K x 128] weights into MFMA fragment order, with per-weight scale:
// P[((ks*8+nt)*64+lane)*8+i] = scale * W[(32ks+8*(lane>>4)+i)*128 + 16nt+(lane&15)]
// W1 (K=50): row k==50 holds scale*b1 (bias folded via f_ij pad element = 1).
// W1 scaled by log2e; W2 scaled by ln2 (ssp computed in log2 domain).
__global__ __launch_bounds__(256) void pack_all(
    const float* __restrict__ W1, const float* __restrict__ b1,
    const float* __restrict__ W2, const float* __restrict__ Wi,
    const float* __restrict__ Wo,
    unsigned short* __restrict__ P1, unsigned short* __restrict__ P2,
    unsigned short* __restrict__ Pi, unsigned short* __restrict__ Po)
{
    int blk = blockIdx.x;
    const float* W; const float* bias = nullptr; unsigned short* P; int K, id;
    float scale;
    if (blk < 32)       { W = W1; P = P1; K = 50;  id = blk * 256 + threadIdx.x; bias = b1;
                          scale = 1.44269504088896340736f; }
    else if (blk < 96)  { W = W2; P = P2; K = 128; id = (blk - 32) * 256 + threadIdx.x;
                          scale = 0.69314718055994530942f; }
    else if (blk < 160) { W = Wi; P = Pi; K = 128; id = (blk - 96) * 256 + threadIdx.x;
                          scale = 1.f; }
    else                { W = Wo; P = Po; K = 128; id = (blk - 160) * 256 + threadIdx.x;
                          scale = 1.f; }
    int i    = id & 7;
    int lane = (id >> 3) & 63;
    int nt   = (id >> 9) & 7;
    int ks   = id >> 12;
    int k = 32 * ks + 8 * (lane >> 4) + i;
    int f = 16 * nt + (lane & 15);
    float v = (k < K) ? W[k * F_ + f] : ((bias && k == K) ? bias[f] : 0.f);
    P[id] = f2bf(scale * v);
}

// out[R x 128] = (ACT? ssp : id)(A[R x 128] @ Bpacked + bias). 1 wave per 16 rows.
template <bool ACT, bool OUT_BF16>
__global__ __launch_bounds__(64) void rowgemm_kernel(
    const float* Afp, const unsigned short* __restrict__ Bp,
    const float* __restrict__ bias, void* outv)
{
    const int l  = threadIdx.x;
    const int r0 = blockIdx.x * 16;
    const bf16x8* Bv = (const bf16x8*)Bp;

    f32x4 acc[8];
    #pragma unroll
    for (int nt = 0; nt < 8; ++nt) acc[nt] = f32x4{0.f, 0.f, 0.f, 0.f};

    const int arow = r0 + (l & 15);
    const int koff = (l >> 4) * 8;
    #pragma unroll
    for (int ks = 0; ks < 4; ++ks) {
        const float* ap = Afp + (size_t)arow * F_ + ks * 32 + koff;
        float4 a0 = *(const float4*)ap;
        float4 a1 = *(const float4*)(ap + 4);
        bf16x8 af;
        af[0] = (short)f2bf(a0.x); af[1] = (short)f2bf(a0.y);
        af[2] = (short)f2bf(a0.z); af[3] = (short)f2bf(a0.w);
        af[4] = (short)f2bf(a1.x); af[5] = (short)f2bf(a1.y);
        af[6] = (short)f2bf(a1.z); af[7] = (short)f2bf(a1.w);
        #pragma unroll
        for (int nt = 0; nt < 8; ++nt) {
            bf16x8 bf = Bv[(ks * 8 + nt) * 64 + l];
            acc[nt] = __builtin_amdgcn_mfma_f32_16x16x32_bf16(af, bf, acc[nt], 0, 0, 0);
        }
    }
    #pragma unroll
    for (int nt = 0; nt < 8; ++nt) {
        int f = nt * 16 + (l & 15);
        float bv = bias ? bias[f] : 0.f;
        #pragma unroll
        for (int r = 0; r < 4; ++r) {
            int orow = r0 + (l >> 4) * 4 + r;
            float v = acc[nt][r] + bv;
            if (ACT) v = sspf(v);
            if (OUT_BF16) ((unsigned short*)outv)[(size_t)orow * F_ + f] = f2bf(v);
            else          ((float*)outv)[(size_t)orow * F_ + f] = v;
        }
    }
}

// 4 atoms/block; double-buffered fij AND H; ONE barrier per atom (48 KB LDS).
__global__ __launch_bounds__(256, 3) void cfconv_main(
    const unsigned short* __restrict__ xt,   // [B*A][F] bf16
    const float* __restrict__ mask,          // [B,A,N]
    const int*   __restrict__ nbr,           // [B,A,N]
    const float* __restrict__ fij,           // [B,A,N,G]
    const unsigned short* __restrict__ W1s,  // packed*log2e, K=50 (+bias row 50)
    const unsigned short* __restrict__ W2s,  // packed*ln2, K=128
    const float* __restrict__ bf2,
    float* __restrict__ Y)                   // [B*A][F] pre-output
{
    const int bid = blockIdx.x;
    const int swz = (bid & 7) * (2048 / 8) + (bid >> 3);   // XCD-bijective (2048%8==0)
    const int ba0 = swz * ATOMS;
    const int t   = threadIdx.x;
    const int w   = t >> 6;
    const int l   = t & 63;
    const int l16 = l & 15;
    const int q   = l >> 4;

    __shared__ unsigned short s_fp[2][4096];  // fij frags, dbuf, 8 KB each
    __shared__ unsigned short s_hp[2][8192];  // H frags, dbuf, 16 KB each

    // ---- uniform base for gathers (SADDR form) ----
    const unsigned short* xt_b = xt + ((size_t)(ba0 >> 10) << 10) * F_;
    const int xoff = 32 * w + 4 * q;

    // ---- W fragments + bias resident for the whole block ----
    const bf16x8* w1v = (const bf16x8*)W1s;
    const bf16x8* w2v = (const bf16x8*)W2s;
    bf16x8 W1r[2][2], W2r[4][2];
    #pragma unroll
    for (int ks = 0; ks < 2; ++ks) {
        W1r[ks][0] = w1v[(ks * 8 + 2 * w + 0) * 64 + l];
        W1r[ks][1] = w1v[(ks * 8 + 2 * w + 1) * 64 + l];
    }
    #pragma unroll
    for (int ks = 0; ks < 4; ++ks) {
        W2r[ks][0] = w2v[(ks * 8 + 2 * w + 0) * 64 + l];
        W2r[ks][1] = w2v[(ks * 8 + 2 * w + 1) * 64 + l];
    }
    f32x4 b2acc[2];
    {
        float4 t0 = *(const float4*)(bf2 + 16 * (2 * w + 0) + 4 * q);
        float4 t1 = *(const float4*)(bf2 + 16 * (2 * w + 1) + 4 * q);
        b2acc[0] = f32x4{t0.x, t0.y, t0.z, t0.w};
        b2acc[1] = f32x4{t1.x, t1.y, t1.z, t1.w};
    }

    // ---- prologue: atom 0 inputs ----
    int nbv[4]; float mkv[4];
    {
        const int*   nb0 = nbr  + (size_t)ba0 * N_;
        const float* mk0 = mask + (size_t)ba0 * N_;
        #pragma unroll
        for (int nt = 0; nt < 4; ++nt) {
            nbv[nt] = nb0[16 * nt + l16];
            mkv[nt] = mk0[16 * nt + l16];
        }
    }
    float2 fa[4], fb[4];
    {
        const float* frow = fij + (size_t)ba0 * (N_ * G_) + (16 * w + l16) * G_;
        #pragma unroll
        for (int j = 0; j < 4; ++j) fa[j] = *(const float2*)(frow + 8 * q + 2 * j);
        if (q < 2) {
            #pragma unroll
            for (int j = 0; j < 4; ++j) fb[j] = *(const float2*)(frow + 32 + 8 * q + 2 * j);
        } else if (q == 2) {
            fb[0] = *(const float2*)(frow + 48);
            fb[1] = float2{1.f, 0.f};  // g=50: bias row of W1
            fb[2] = float2{0.f, 0.f}; fb[3] = float2{0.f, 0.f};
        } else {
            #pragma unroll
            for (int j = 0; j < 4; ++j) fb[j] = float2{0.f, 0.f};
        }
    }
    uint2 xg[2][4];
    #pragma unroll
    for (int f2 = 0; f2 < 2; ++f2)
        #pragma unroll
        for (int nt = 0; nt < 4; ++nt)
            xg[f2][nt] = *(const uint2*)(xt_b + nbv[nt] * F_ + xoff + 16 * f2);
    {
        uint4 pk0, pk1;
        pk0.x = cvt_pk(fa[0].x, fa[0].y); pk0.y = cvt_pk(fa[1].x, fa[1].y);
        pk0.z = cvt_pk(fa[2].x, fa[2].y); pk0.w = cvt_pk(fa[3].x, fa[3].y);
        pk1.x = cvt_pk(fb[0].x, fb[0].y); pk1.y = cvt_pk(fb[1].x, fb[1].y);
        pk1.z = cvt_pk(fb[2].x, fb[2].y); pk1.w = cvt_pk(fb[3].x, fb[3].y);
        *(uint4*)(&s_fp[0][((w * 2 + 0) * 64 + l) * 8]) = pk0;
        *(uint4*)(&s_fp[0][((w * 2 + 1) * 64 + l) * 8]) = pk1;
    }
    __syncthreads();

    int nbv2[4]; float mkv2[4];

    #pragma unroll
    for (int i = 0; i < ATOMS; ++i) {
        const int ba = ba0 + i;
        const bf16x8* fv = (const bf16x8*)s_fp[i & 1];
        unsigned short* fp_nxt = s_fp[(i + 1) & 1];
        unsigned short* hp_cur = s_hp[i & 1];

        // ---- GEMM1 (ks=0 peeled with zero C): acc1[ct2][nt] ----
        f32x4 acc1[2][4];
        __builtin_amdgcn_s_setprio(1);
        {
            bf16x8 bb[4];
            #pragma unroll
            for (int nt = 0; nt < 4; ++nt) bb[nt] = fv[(nt * 2 + 0) * 64 + l];
            #pragma unroll
            for (int nt = 0; nt < 4; ++nt) {
                acc1[0][nt] = __builtin_amdgcn_mfma_f32_16x16x32_bf16(W1r[0][0], bb[nt], f32x4{0.f,0.f,0.f,0.f}, 0, 0, 0);
                acc1[1][nt] = __builtin_amdgcn_mfma_f32_16x16x32_bf16(W1r[0][1], bb[nt], f32x4{0.f,0.f,0.f,0.f}, 0, 0, 0);
            }
            #pragma unroll
            for (int nt = 0; nt < 4; ++nt) bb[nt] = fv[(nt * 2 + 1) * 64 + l];
            #pragma unroll
            for (int nt = 0; nt < 4; ++nt) {
                acc1[0][nt] = __builtin_amdgcn_mfma_f32_16x16x32_bf16(W1r[1][0], bb[nt], acc1[0][nt], 0, 0, 0);
                acc1[1][nt] = __builtin_amdgcn_mfma_f32_16x16x32_bf16(W1r[1][1], bb[nt], acc1[1][nt], 0, 0, 0);
            }
        }
        __builtin_amdgcn_s_setprio(0);

        // ---- issue next atom's fij + nbr/mask (fly under epilogue; short live range) ----
        if (i < ATOMS - 1) {
            const float* frow = fij + (size_t)(ba + 1) * (N_ * G_) + (16 * w + l16) * G_;
            #pragma unroll
            for (int j = 0; j < 4; ++j) fa[j] = *(const float2*)(frow + 8 * q + 2 * j);
            if (q < 2) {
                #pragma unroll
                for (int j = 0; j < 4; ++j) fb[j] = *(const float2*)(frow + 32 + 8 * q + 2 * j);
            } else if (q == 2) {
                fb[0] = *(const float2*)(frow + 48);
                fb[1] = float2{1.f, 0.f};
                fb[2] = float2{0.f, 0.f}; fb[3] = float2{0.f, 0.f};
            } else {
                #pragma unroll
                for (int j = 0; j < 4; ++j) fb[j] = float2{0.f, 0.f};
            }
            const int*   nb1 = nbr  + (size_t)(ba + 1) * N_;
            const float* mk1 = mask + (size_t)(ba + 1) * N_;
            #pragma unroll
            for (int nt = 0; nt < 4; ++nt) {
                nbv2[nt] = nb1[16 * nt + l16];
                mkv2[nt] = mk1[16 * nt + l16];
            }
        }

        // ---- H epilogue: ssp2 -> B-frag layout into hp[i&1] ----
        #pragma unroll
        for (int ct2 = 0; ct2 < 2; ++ct2) {
            const int addr = ((w * 64 + 16 * (2 * ct2 + (q >> 1)) + l16) * 8 + 4 * (q & 1));
            #pragma unroll
            for (int nt = 0; nt < 4; ++nt) {
                float h0 = ssp2(acc1[ct2][nt][0]);
                float h1 = ssp2(acc1[ct2][nt][1]);
                float h2 = ssp2(acc1[ct2][nt][2]);
                float h3 = ssp2(acc1[ct2][nt][3]);
                uint2 pk;
                pk.x = cvt_pk(h0, h1);
                pk.y = cvt_pk(h2, h3);
                *(uint2*)(&hp_cur[nt * 2048 + addr]) = pk;
            }
        }

        // ---- stage next fij frags into the OTHER fij buffer ----
        if (i < ATOMS - 1) {
            uint4 pk0, pk1;
            pk0.x = cvt_pk(fa[0].x, fa[0].y); pk0.y = cvt_pk(fa[1].x, fa[1].y);
            pk0.z = cvt_pk(fa[2].x, fa[2].y); pk0.w = cvt_pk(fa[3].x, fa[3].y);
            pk1.x = cvt_pk(fb[0].x, fb[0].y); pk1.y = cvt_pk(fb[1].x, fb[1].y);
            pk1.z = cvt_pk(fb[2].x, fb[2].y); pk1.w = cvt_pk(fb[3].x, fb[3].y);
            *(uint4*)(&fp_nxt[((w * 2 + 0) * 64 + l) * 8]) = pk0;
            *(uint4*)(&fp_nxt[((w * 2 + 1) * 64 + l) * 8]) = pk1;
        }
        __syncthreads();   // ONE barrier per atom: H(i) + fp(i+1) ready

        // ---- GEMM2 (ks=0 peeled with C = bias2): acc2[f2][nt] ----
        const bf16x8* hv = (const bf16x8*)hp_cur;
        f32x4 acc2[2][4];
        __builtin_amdgcn_s_setprio(1);
        {
            bf16x8 bb[4];
            #pragma unroll
            for (int nt = 0; nt < 4; ++nt) bb[nt] = hv[(nt * 4 + 0) * 64 + l];
            #pragma unroll
            for (int nt = 0; nt < 4; ++nt) {
                acc2[0][nt] = __builtin_amdgcn_mfma_f32_16x16x32_bf16(W2r[0][0], bb[nt], b2acc[0], 0, 0, 0);
                acc2[1][nt] = __builtin_amdgcn_mfma_f32_16x16x32_bf16(W2r[0][1], bb[nt], b2acc[1], 0, 0, 0);
            }
            #pragma unroll
            for (int ks = 1; ks < 4; ++ks) {
                #pragma unroll
                for (int nt = 0; nt < 4; ++nt) bb[nt] = hv[(nt * 4 + ks) * 64 + l];
                #pragma unroll
                for (int nt = 0; nt < 4; ++nt) {
                    acc2[0][nt] = __builtin_amdgcn_mfma_f32_16x16x32_bf16(W2r[ks][0], bb[nt], acc2[0][nt], 0, 0, 0);
                    acc2[1][nt] = __builtin_amdgcn_mfma_f32_16x16x32_bf16(W2r[ks][1], bb[nt], acc2[1][nt], 0, 0, 0);
                }
            }
        }
        __builtin_amdgcn_s_setprio(0);

        // ---- reduce over m: filter * mask * x, DPP butterfly, store ----
        #pragma unroll
        for (int f2 = 0; f2 < 2; ++f2) {
            float p0 = 0.f, p1 = 0.f, p2 = 0.f, p3 = 0.f;
            #pragma unroll
            for (int nt = 0; nt < 4; ++nt) {
                const float msk = mkv[nt];
                const uint2 xv = xg[f2][nt];
                const float x0 = __uint_as_float(xv.x << 16);
                const float x1 = __uint_as_float(xv.x & 0xffff0000u);
                const float x2 = __uint_as_float(xv.y << 16);
                const float x3 = __uint_as_float(xv.y & 0xffff0000u);
                p0 = fmaf(msk * acc2[f2][nt][0], x0, p0);
                p1 = fmaf(msk * acc2[f2][nt][1], x1, p1);
                p2 = fmaf(msk * acc2[f2][nt][2], x2, p2);
                p3 = fmaf(msk * acc2[f2][nt][3], x3, p3);
            }
            p0 = red16(p0); p1 = red16(p1); p2 = red16(p2); p3 = red16(p3);
            if (l16 == 0)
                *(float4*)(Y + (size_t)ba * F_ + 16 * (2 * w + f2) + 4 * q) = float4{p0, p1, p2, p3};
        }

        // ---- roll inputs; issue next xg gathers (fly under next GEMM1+epilogue) ----
        if (i < ATOMS - 1) {
            #pragma unroll
            for (int nt = 0; nt < 4; ++nt) { nbv[nt] = nbv2[nt]; mkv[nt] = mkv2[nt]; }
            #pragma unroll
            for (int f2 = 0; f2 < 2; ++f2)
                #pragma unroll
                for (int nt = 0; nt < 4; ++nt)
                    xg[f2][nt] = *(const uint2*)(xt_b + nbv[nt] * F_ + xoff + 16 * f2);
        }
        // no second barrier: hp is double-buffered; fp overwrite is fenced by the
        // next atom's barrier (any wave writing fp[(i+2)&1] has passed barrier(i+1),
        // which requires all waves done reading it in GEMM1(i)).
    }
}

extern "C" void kernel_launch(void* const* d_in, const int* in_sizes, int n_in,
                              void* d_out, int out_size, void* d_ws, size_t ws_size,
                              hipStream_t stream) {
    const float* x     = (const float*)d_in[0];
    const float* mask  = (const float*)d_in[1];
    const int*   nbr   = (const int*)d_in[2];
    const float* fij   = (const float*)d_in[3];
    const float* Wf1   = (const float*)d_in[4];
    const float* bf1   = (const float*)d_in[5];
    const float* Wf2   = (const float*)d_in[6];
    const float* bf2   = (const float*)d_in[7];
    const float* Win2f = (const float*)d_in[8];
    const float* Wout  = (const float*)d_in[9];
    const float* bout  = (const float*)d_in[10];
    float* out = (float*)d_out;

    char* ws = (char*)d_ws;
    unsigned short* W1p   = (unsigned short*)(ws);            // 16 KB
    unsigned short* W2p   = (unsigned short*)(ws + 16384);    // 32 KB
    unsigned short* Winp  = (unsigned short*)(ws + 49152);    // 32 KB
    unsigned short* Woutp = (unsigned short*)(ws + 81920);    // 32 KB
    unsigned short* xt    = (unsigned short*)(ws + 114688);   // 2 MB

    pack_all<<<224, 256, 0, stream>>>(Wf1, bf1, Wf2, Win2f, Wout, W1p, W2p, Winp, Woutp);

    rowgemm_kernel<false, true><<<B_ * A_ / 16, 64, 0, stream>>>(x, Winp, nullptr, xt);

    cfconv_main<<<B_ * A_ / ATOMS, 256, 0, stream>>>(xt, mask, nbr, fij, W1p, W2p, bf2, out);

    rowgemm_kernel<true, false><<<B_ * A_ / 16, 64, 0, stream>>>(out, Woutp, bout, out);
}